// Round 10
// baseline (10293.789 us; speedup 1.0000x reference)
//
#include <hip/hip_runtime.h>

// ---------------------------------------------------------------------------
// Euler Attention, gfx950 — ROUND 10: FP32 OUTPUT (harness docstring: output
// dtype = reference output dtype = float32 -> float*). All rounds 2-9 wrote
// bf16 (8MB) into what is likely a 16MB fp32 buffer; first half read back as
// packed-pair garbage (-> the persistent ~7.2 decorrelation), second half
// stayed zero (-> r0's 5.0). This round: r5's trusted scalar fp32 pipeline
// verbatim (dict order, C-order X, NT weights), fp32 output.
// ---------------------------------------------------------------------------

#define BB 2
#define LL 2048
#define DD 1024
#define HH 16
#define DH 64

__device__ __forceinline__ float waveMax(float v) {
#pragma unroll
  for (int m = 32; m > 0; m >>= 1) v = fmaxf(v, __shfl_xor(v, m));
  return v;
}
__device__ __forceinline__ float waveSum(float v) {
#pragma unroll
  for (int m = 32; m > 0; m >>= 1) v += __shfl_xor(v, m);
  return v;
}

// NT: C[M x N] = A[M x K] * B[N x K]^T (+bias)   (reference: x @ W.T + b)
__global__ __launch_bounds__(256) void sgemm_nt(const float* __restrict__ A,
                                                const float* __restrict__ B,
                                                const float* __restrict__ bias,
                                                float* __restrict__ C,
                                                int M, int N, int K) {
  __shared__ float As[16][17], Bs[16][17];
  const int tx = threadIdx.x & 15, ty = threadIdx.x >> 4;
  const int row = blockIdx.y * 16 + ty;
  const int col = blockIdx.x * 16 + tx;
  float acc = 0.f;
  for (int k0 = 0; k0 < K; k0 += 16) {
    As[ty][tx] = A[(size_t)row * K + k0 + tx];
    Bs[ty][tx] = B[(size_t)(blockIdx.x * 16 + ty) * K + k0 + tx];
    __syncthreads();
#pragma unroll
    for (int kk = 0; kk < 16; ++kk) acc += As[ty][kk] * Bs[tx][kk];
    __syncthreads();
  }
  if (bias) acc += bias[col];
  C[(size_t)row * N + col] = acc;
}

// scores[b][i] = mean over L of A[b][l][i]
__global__ __launch_bounds__(256) void colmean(const float* __restrict__ A,
                                               float* __restrict__ outv) {
  const int i = blockIdx.x * 256 + threadIdx.x;
  const int b = blockIdx.y;
  const float* base = A + (size_t)b * LL * DD;
  float s = 0.f;
  for (int l = 0; l < LL; ++l) s += base[(size_t)l * DD + i];
  outv[b * DD + i] = s * (1.f / (float)LL);
}

// Bsum[b][j] = sum_m |s_j - s_m|
__global__ __launch_bounds__(1024) void bsum_k(const float* __restrict__ sc2,
                                               float* __restrict__ bs2) {
  __shared__ float sc[DD];
  const int b = blockIdx.x, tid = threadIdx.x;
  sc[tid] = sc2[b * DD + tid];
  __syncthreads();
  const float si = sc[tid];
  float s = 0.f;
  for (int j = 0; j < DD; ++j) s += fabsf(si - sc[j]);
  bs2[b * DD + tid] = s;
}

// P[b][i][j] = softmax_j( s_j*(1023-2i) - Bsum_j )
__global__ __launch_bounds__(256) void p_k(const float* __restrict__ sc2,
                                           const float* __restrict__ bs2,
                                           float* __restrict__ P) {
  const int i = blockIdx.x, b = blockIdx.y, tid = threadIdx.x;
  const float* sc = sc2 + b * DD;
  const float* bs = bs2 + b * DD;
  const float scal = 1023.f - 2.f * (float)i;
  __shared__ float redA[4], redB[4];
  float lg[4];
  float mx = -1e30f;
#pragma unroll
  for (int s = 0; s < 4; ++s) {
    const int j = tid + s * 256;
    lg[s] = sc[j] * scal - bs[j];
    mx = fmaxf(mx, lg[s]);
  }
  mx = waveMax(mx);
  if ((tid & 63) == 0) redA[tid >> 6] = mx;
  __syncthreads();
  const float M = fmaxf(fmaxf(redA[0], redA[1]), fmaxf(redA[2], redA[3]));
  float sum = 0.f;
#pragma unroll
  for (int s = 0; s < 4; ++s) { lg[s] = expf(lg[s] - M); sum += lg[s]; }
  sum = waveSum(sum);
  if ((tid & 63) == 0) redB[tid >> 6] = sum;
  __syncthreads();
  const float inv = 1.f / (redB[0] + redB[1] + redB[2] + redB[3]);
  float* Pr = P + (size_t)b * DD * DD + (size_t)i * DD;
#pragma unroll
  for (int s = 0; s < 4; ++s) Pr[tid + s * 256] = lg[s] * inv;
}

// euler transform, fp32 in-place
__global__ __launch_bounds__(256) void euler_f(float* __restrict__ buf,
                                               const float* __restrict__ delta,
                                               const float* __restrict__ beul,
                                               const float* __restrict__ lsc,
                                               int isq) {
  const int idx = blockIdx.x * 256 + threadIdx.x;
  const int c = idx & 511;
  const size_t n = idx >> 9;
  const float r = buf[n * DD + 2 * c];
  const float p = buf[n * DD + 2 * c + 1];
  float lam = sqrtf(r * r + p * p + 1e-6f);
  float th = atan2f(p, r) * delta[c];
  if (isq) th += beul[c];
  lam *= expf(fminf(fmaxf(lsc[c], -5.f), 5.f));
  buf[n * DD + 2 * c]     = lam * cosf(th);
  buf[n * DD + 2 * c + 1] = lam * sinf(th);
}

// scalar attention, fp32 throughout
__global__ __launch_bounds__(256) void attn_scalar(const float* __restrict__ Q,
                                                   const float* __restrict__ K,
                                                   const float* __restrict__ V,
                                                   float* __restrict__ O) {
  const int qrow = blockIdx.x, h = blockIdx.y, b = blockIdx.z;
  __shared__ float qv[64];
  __shared__ float pb[LL];
  __shared__ float red[8];
  __shared__ float ctxred[4][64];
  const size_t base = ((size_t)b * LL) * DD + (size_t)h * DH;
  const int tid = threadIdx.x;
  if (tid < 64) qv[tid] = Q[base + (size_t)qrow * DD + tid];
  __syncthreads();
  float sv[8];
  float smax = -1e30f;
#pragma unroll
  for (int kk = 0; kk < 8; ++kk) {
    const int k = tid * 8 + kk;
    const float* kr = K + base + (size_t)k * DD;
    float s = 0.f;
    for (int d = 0; d < 64; ++d) s += qv[d] * kr[d];
    sv[kk] = s * 0.125f;
    smax = fmaxf(smax, sv[kk]);
  }
  smax = waveMax(smax);
  if ((tid & 63) == 0) red[tid >> 6] = smax;
  __syncthreads();
  const float M = fmaxf(fmaxf(red[0], red[1]), fmaxf(red[2], red[3]));
  float ssum = 0.f;
#pragma unroll
  for (int kk = 0; kk < 8; ++kk) {
    sv[kk] = expf(sv[kk] - M);
    ssum += sv[kk];
    pb[tid * 8 + kk] = sv[kk];
  }
  ssum = waveSum(ssum);
  if ((tid & 63) == 0) red[4 + (tid >> 6)] = ssum;
  __syncthreads();
  const float S = red[4] + red[5] + red[6] + red[7];
  const int d = tid & 63, ch = tid >> 6;
  float acc = 0.f;
  for (int k = ch * 512; k < ch * 512 + 512; ++k)
    acc += pb[k] * V[base + (size_t)k * DD + d];
  ctxred[ch][d] = acc;
  __syncthreads();
  if (tid < 64) {
    const float c = (ctxred[0][tid] + ctxred[1][tid] + ctxred[2][tid] + ctxred[3][tid]) / S;
    O[base + (size_t)qrow * DD + tid] = c;
  }
}

// layernorm(hidden + X) * gamma + beta -> FP32 out
__global__ __launch_bounds__(256) void ln_k(const float* __restrict__ hidden,
                                            const float* __restrict__ x0,
                                            const float* __restrict__ gamma,
                                            const float* __restrict__ beta,
                                            float* __restrict__ out) {
  const int row = blockIdx.x, tid = threadIdx.x;
  __shared__ float red1[4], red2[4];
  float v[4];
  float s1 = 0.f, s2 = 0.f;
#pragma unroll
  for (int s = 0; s < 4; ++s) {
    const int c = tid + s * 256;
    const float x = hidden[(size_t)row * DD + c] + x0[(size_t)row * DD + c];
    v[s] = x; s1 += x; s2 += x * x;
  }
  s1 = waveSum(s1); s2 = waveSum(s2);
  if ((tid & 63) == 0) { red1[tid >> 6] = s1; red2[tid >> 6] = s2; }
  __syncthreads();
  const float t1 = red1[0] + red1[1] + red1[2] + red1[3];
  const float t2 = red2[0] + red2[1] + red2[2] + red2[3];
  const float mu = t1 * (1.f / DD);
  const float var = t2 * (1.f / DD) - mu * mu;
  const float inv = rsqrtf(var + 1e-12f);
#pragma unroll
  for (int s = 0; s < 4; ++s) {
    const int c = tid + s * 256;
    out[(size_t)row * DD + c] = (v[s] - mu) * inv * gamma[c] + beta[c];
  }
}

// ---------------------------------------------------------------------------
extern "C" void kernel_launch(void* const* d_in, const int* in_sizes, int n_in,
                              void* d_out, int out_size, void* d_ws, size_t ws_size,
                              hipStream_t stream) {
  const float* X    = (const float*)d_in[0];
  const float* Wq   = (const float*)d_in[1];
  const float* bq   = (const float*)d_in[2];
  const float* Wk   = (const float*)d_in[3];
  const float* bk   = (const float*)d_in[4];
  const float* Wv   = (const float*)d_in[5];
  const float* bv   = (const float*)d_in[6];
  const float* Wd   = (const float*)d_in[7];
  const float* bd   = (const float*)d_in[8];
  const float* gam  = (const float*)d_in[9];
  const float* bet  = (const float*)d_in[10];
  const float* delt = (const float*)d_in[11];
  const float* beul = (const float*)d_in[12];
  const float* lsc  = (const float*)d_in[13];
  float* out = (float*)d_out;

  char* w = (char*)d_ws;
  const size_t MB = 1024ull * 1024ull;
  float* qf  = (float*)(w + 0 * MB);    // 16MB; kf, vf overlay sequentially
  float* kf  = (float*)(w + 0 * MB);
  float* vf  = (float*)(w + 0 * MB);
  float* Pq  = (float*)(w + 16 * MB);   // 8MB; Pk overlays
  float* Pk  = (float*)(w + 16 * MB);
  float* qs  = (float*)(w + 24 * MB);   // 16MB; hid overlays after attn
  float* hid = (float*)(w + 24 * MB);
  float* ks  = (float*)(w + 40 * MB);   // 16MB
  float* ctx = (float*)(w + 56 * MB);   // 16MB
  float* scores = (float*)(w + 72 * MB);
  float* bsum   = (float*)(w + 72 * MB + 8 * 1024);

  // ---- q pipeline ----
  sgemm_nt<<<dim3(64, 256), 256, 0, stream>>>(X, Wq, bq, qf, BB * LL, DD, DD);
  colmean<<<dim3(4, 2), 256, 0, stream>>>(qf, scores);
  bsum_k<<<dim3(2), 1024, 0, stream>>>(scores, bsum);
  p_k<<<dim3(1024, 2), 256, 0, stream>>>(scores, bsum, Pq);
  for (int b = 0; b < BB; ++b)
    sgemm_nt<<<dim3(64, 128), 256, 0, stream>>>(qf + (size_t)b * LL * DD,
                                                Pq + (size_t)b * DD * DD, nullptr,
                                                qs + (size_t)b * LL * DD, LL, DD, DD);
  euler_f<<<dim3(8192), 256, 0, stream>>>(qs, delt, beul, lsc, 1);

  // ---- k pipeline (kf overlays dead qf) ----
  sgemm_nt<<<dim3(64, 256), 256, 0, stream>>>(X, Wk, bk, kf, BB * LL, DD, DD);
  colmean<<<dim3(4, 2), 256, 0, stream>>>(kf, scores);
  bsum_k<<<dim3(2), 1024, 0, stream>>>(scores, bsum);
  p_k<<<dim3(1024, 2), 256, 0, stream>>>(scores, bsum, Pk);
  for (int b = 0; b < BB; ++b)
    sgemm_nt<<<dim3(64, 128), 256, 0, stream>>>(kf + (size_t)b * LL * DD,
                                                Pk + (size_t)b * DD * DD, nullptr,
                                                ks + (size_t)b * LL * DD, LL, DD, DD);
  euler_f<<<dim3(8192), 256, 0, stream>>>(ks, delt, beul, lsc, 0);

  // ---- v projection (vf overlays dead kf) ----
  sgemm_nt<<<dim3(64, 256), 256, 0, stream>>>(X, Wv, bv, vf, BB * LL, DD, DD);

  // ---- attention ----
  attn_scalar<<<dim3(LL, HH, BB), 256, 0, stream>>>(qs, ks, vf, ctx);

  // ---- output projection (hid overlays dead qs) ----
  sgemm_nt<<<dim3(64, 256), 256, 0, stream>>>(ctx, Wd, bd, hid, BB * LL, DD, DD);

  // ---- layernorm + residual, FP32 C-order output ----
  ln_k<<<dim3(BB * LL), 256, 0, stream>>>(hid, X, gam, bet, out);
}

// Round 11
// 536.978 us; speedup vs baseline: 19.1698x; 19.1698x over previous
//
#include <hip/hip_runtime.h>

// ---------------------------------------------------------------------------
// Euler Attention forward, MI355X gfx950 — ROUND 11: MFMA pipeline restored.
// Established (r10 PASS): inputs fp32 dict-order C-layout, OUTPUT FP32.
//   0) cast X, Wq,Wk,Wv,Wd  fp32 -> bf16 (for MFMA)
//   1) qkv = X @ {Wq,Wk,Wv}^T + b          (MFMA bf16 GEMM, bf16 out)
//   2) xmean = mean_L(X); scores = xmean @ {Wq,Wk}^T + b   (exact fp32)
//   3) Bsum, P = neural_sort(scores)        (fp32 softmax rows -> bf16 P)
//   4) q_sorted = q @ P^T per batch         (MFMA GEMM, bf16 out)
//   5) euler transform in-place (bf16)
//   6) flash attention (64x64 MFMA tiles, online softmax) -> bf16 ctx
//   7) hidden = ctx @ Wd^T + bd             (MFMA GEMM, fp32 out)
//   8) layernorm(hidden + X) -> FP32 out
// Workspace peak 72 MB + 40 KB (proven safe).
// ---------------------------------------------------------------------------

typedef unsigned short bf16_t;
typedef short frag_ab __attribute__((ext_vector_type(8)));   // 8 bf16 = 4 VGPRs
typedef float frag_cd __attribute__((ext_vector_type(4)));   // 4 fp32 acc

#define BB 2
#define LL 2048
#define DD 1024
#define HH 16
#define DH 64

__device__ __forceinline__ float b2f(bf16_t u) {
  union { unsigned int i; float f; } c; c.i = ((unsigned int)u) << 16; return c.f;
}
__device__ __forceinline__ bf16_t f2b(float f) {
  union { float f; unsigned int i; } c; c.f = f;
  unsigned int r = c.i + 0x7fffu + ((c.i >> 16) & 1u);
  return (bf16_t)(r >> 16);
}
__device__ __forceinline__ float waveMax(float v) {
#pragma unroll
  for (int m = 32; m > 0; m >>= 1) v = fmaxf(v, __shfl_xor(v, m));
  return v;
}
__device__ __forceinline__ float waveSum(float v) {
#pragma unroll
  for (int m = 32; m > 0; m >>= 1) v += __shfl_xor(v, m);
  return v;
}

// fp32 -> bf16 cast, 4 elems/thread
__global__ __launch_bounds__(256) void cast_f2b(const float* __restrict__ in,
                                                bf16_t* __restrict__ out, int n4) {
  const int i = blockIdx.x * 256 + threadIdx.x;
  if (i < n4) {
    float4 v = ((const float4*)in)[i];
    ushort4 o;
    o.x = f2b(v.x); o.y = f2b(v.y); o.z = f2b(v.z); o.w = f2b(v.w);
    ((ushort4*)out)[i] = o;
  }
}

// ---------------------------------------------------------------------------
// 128x128 tile MFMA GEMM, C = A * B^T (+bias). A: MxK bf16 row-major,
// B: NxK bf16 row-major. 256 thr, 4 waves 2x2, 4x4 grid of 16x16x32 MFMAs.
// ---------------------------------------------------------------------------
struct GemmB { const bf16_t* A; const bf16_t* Bm; const float* bias; float* Cf; bf16_t* Cb; };
struct GemmArgs { GemmB gb[4]; };

__global__ __launch_bounds__(256) void gemm128(GemmArgs ga, int M, int N, int K) {
  const GemmB g = ga.gb[blockIdx.z];
  const int bm = blockIdx.y * 128, bn = blockIdx.x * 128;
  __shared__ bf16_t As[128][32];
  __shared__ bf16_t Bs[128][32];
  const int tid = threadIdx.x;
  const int lane = tid & 63, w = tid >> 6;
  const int quad = lane >> 4, l16 = lane & 15;
  const int wm = (w >> 1) * 64, wn = (w & 1) * 64;

  frag_cd acc[4][4];
#pragma unroll
  for (int i = 0; i < 4; ++i)
#pragma unroll
    for (int j = 0; j < 4; ++j)
#pragma unroll
      for (int r = 0; r < 4; ++r) acc[i][j][r] = 0.f;

  const int r0 = tid >> 2, s0 = (tid & 3) * 8;
  const int r1 = (tid + 256) >> 2, s1 = ((tid + 256) & 3) * 8;
  const size_t aoff0 = (size_t)(bm + r0) * K + s0;
  const size_t aoff1 = (size_t)(bm + r1) * K + s1;
  const size_t boff0 = (size_t)(bn + r0) * K + s0;
  const size_t boff1 = (size_t)(bn + r1) * K + s1;

  for (int k0 = 0; k0 < K; k0 += 32) {
    uint4 a0 = *(const uint4*)(g.A + aoff0 + k0);
    uint4 a1 = *(const uint4*)(g.A + aoff1 + k0);
    uint4 b0 = *(const uint4*)(g.Bm + boff0 + k0);
    uint4 b1 = *(const uint4*)(g.Bm + boff1 + k0);
    __syncthreads();
    *(uint4*)&As[r0][s0] = a0;
    *(uint4*)&As[r1][s1] = a1;
    *(uint4*)&Bs[r0][s0] = b0;
    *(uint4*)&Bs[r1][s1] = b1;
    __syncthreads();
    frag_ab af[4], bfr[4];
#pragma unroll
    for (int i = 0; i < 4; ++i) {
      af[i]  = *(const frag_ab*)&As[wm + i * 16 + l16][quad * 8];
      bfr[i] = *(const frag_ab*)&Bs[wn + i * 16 + l16][quad * 8];
    }
#pragma unroll
    for (int i = 0; i < 4; ++i)
#pragma unroll
      for (int j = 0; j < 4; ++j)
        acc[i][j] = __builtin_amdgcn_mfma_f32_16x16x32_bf16(af[i], bfr[j], acc[i][j], 0, 0, 0);
  }

#pragma unroll
  for (int i = 0; i < 4; ++i) {
#pragma unroll
    for (int r = 0; r < 4; ++r) {
      const int row = bm + wm + i * 16 + quad * 4 + r;
#pragma unroll
      for (int j = 0; j < 4; ++j) {
        const int col = bn + wn + j * 16 + l16;
        float v = acc[i][j][r];
        if (g.bias) v += g.bias[col];
        if (g.Cf) g.Cf[(size_t)row * N + col] = v;
        if (g.Cb) g.Cb[(size_t)row * N + col] = f2b(v);
      }
    }
  }
}

// xmean[b][d] = mean over L of X[b][l][d]  (fp32, atomic partials)
__global__ __launch_bounds__(256) void xmean_kernel(const float* __restrict__ X,
                                                    float* __restrict__ xmean) {
  const int d = blockIdx.x * 256 + threadIdx.x;
  const int b = blockIdx.z;
  const int l0 = blockIdx.y * 64;
  float s = 0.f;
  for (int l = l0; l < l0 + 64; ++l)
    s += X[((size_t)b * LL + l) * DD + d];
  atomicAdd(&xmean[b * DD + d], s * (1.f / (float)LL));
}

// scores[t][b][i] = sum_j xmean[b][j] * W_t[i][j] + bias_t[i]   (exact fp32)
__global__ __launch_bounds__(256) void scores_gemm(const float* __restrict__ xmean,
                                                   const float* __restrict__ Wq,
                                                   const float* __restrict__ bq,
                                                   const float* __restrict__ Wk,
                                                   const float* __restrict__ bk,
                                                   float* __restrict__ scores) {
  const int idx = blockIdx.x * 256 + threadIdx.x;   // 0..4095
  const int t = idx >> 11, b = (idx >> 10) & 1, i = idx & 1023;
  const float* W = t ? Wk : Wq;
  const float* bias = t ? bk : bq;
  const float* xm = xmean + b * DD;
  float sum = 0.f;
  for (int j = 0; j < DD; j += 4) {
    float4 wv = *(const float4*)&W[(size_t)i * DD + j];
    sum += xm[j] * wv.x + xm[j + 1] * wv.y + xm[j + 2] * wv.z + xm[j + 3] * wv.w;
  }
  scores[idx] = sum + bias[i];
}

// Bsum[z][j] = sum_m |scores[z][j] - scores[z][m]|
__global__ __launch_bounds__(1024) void bsum_kernel(const float* __restrict__ scores,
                                                    float* __restrict__ bsum) {
  __shared__ float sc[DD];
  const int z = blockIdx.x, tid = threadIdx.x;
  sc[tid] = scores[z * DD + tid];
  __syncthreads();
  const float si = sc[tid];
  float s = 0.f;
  for (int j = 0; j < DD; ++j) s += fabsf(si - sc[j]);
  bsum[z * DD + tid] = s;
}

// P[z][i][j] = softmax_j( scores[z][j]*(1023-2i) - Bsum[z][j] )  -> bf16
__global__ __launch_bounds__(256) void p_kernel(const float* __restrict__ scores,
                                                const float* __restrict__ bsum,
                                                bf16_t* __restrict__ Pq,
                                                bf16_t* __restrict__ Pk) {
  const int i = blockIdx.x;
  const int z = blockIdx.y;          // t*2 + b
  const int t = z >> 1, b = z & 1;
  const float* sc = scores + z * DD;
  const float* bs = bsum + z * DD;
  const float scal = 1023.f - 2.f * (float)i;
  const int tid = threadIdx.x;
  __shared__ float redA[4], redB[4];

  float lg[4];
  float mx = -1e30f;
#pragma unroll
  for (int s = 0; s < 4; ++s) {
    const int j = tid + s * 256;
    lg[s] = sc[j] * scal - bs[j];
    mx = fmaxf(mx, lg[s]);
  }
  mx = waveMax(mx);
  if ((tid & 63) == 0) redA[tid >> 6] = mx;
  __syncthreads();
  const float M = fmaxf(fmaxf(redA[0], redA[1]), fmaxf(redA[2], redA[3]));
  float sum = 0.f;
#pragma unroll
  for (int s = 0; s < 4; ++s) {
    lg[s] = __expf(lg[s] - M);
    sum += lg[s];
  }
  sum = waveSum(sum);
  if ((tid & 63) == 0) redB[tid >> 6] = sum;
  __syncthreads();
  const float inv = 1.f / (redB[0] + redB[1] + redB[2] + redB[3]);
  bf16_t* P = (t ? Pk : Pq) + ((size_t)b << 20) + (size_t)i * DD;
#pragma unroll
  for (int s = 0; s < 4; ++s) P[tid + s * 256] = f2b(lg[s] * inv);
}

// euler transform: bf16 in-place, fp32 params
__global__ __launch_bounds__(256) void euler_kernel(bf16_t* __restrict__ buf,
                                                    const float* __restrict__ delta,
                                                    const float* __restrict__ beul,
                                                    const float* __restrict__ lsc,
                                                    int isq) {
  const int idx = blockIdx.x * 256 + threadIdx.x;  // pair index
  const int c = idx & 511;
  const size_t n = idx >> 9;
  const float r = b2f(buf[n * DD + 2 * c]);
  const float p = b2f(buf[n * DD + 2 * c + 1]);
  float lam = sqrtf(r * r + p * p + 1e-6f);
  float th = atan2f(p, r) * delta[c];
  if (isq) th += beul[c];
  lam *= __expf(fminf(fmaxf(lsc[c], -5.f), 5.f));
  float sn, cs;
  __sincosf(th, &sn, &cs);
  buf[n * DD + 2 * c]     = f2b(lam * cs);
  buf[n * DD + 2 * c + 1] = f2b(lam * sn);
}

// ---------------------------------------------------------------------------
// Flash attention: one block per (b, h, 64-row q tile). 4 waves, each 16 q
// rows. K/V staged in LDS 64 at a time; online softmax; P via LDS for the
// C-layout -> A-layout transform.
// ---------------------------------------------------------------------------
__global__ __launch_bounds__(256) void attn_kernel(const bf16_t* __restrict__ Q,
                                                   const bf16_t* __restrict__ Kt,
                                                   const bf16_t* __restrict__ V,
                                                   bf16_t* __restrict__ O) {
  const int b = blockIdx.z, h = blockIdx.y;
  const int q0 = blockIdx.x * 64;
  const int tid = threadIdx.x, w = tid >> 6, lane = tid & 63;
  const int quad = lane >> 4, l16 = lane & 15;
  __shared__ bf16_t Qs[64][64], Ks[64][64], Vt[64][64], Ps[64][64];
  const size_t base = ((size_t)b * LL) * DD + (size_t)h * DH;

  for (int i = tid; i < 512; i += 256) {
    const int r = i >> 3, seg = i & 7;
    *(uint4*)&Qs[r][seg * 8] = *(const uint4*)&Q[base + (size_t)(q0 + r) * DD + seg * 8];
  }
  __syncthreads();
  frag_ab aq0 = *(const frag_ab*)&Qs[w * 16 + l16][quad * 8];
  frag_ab aq1 = *(const frag_ab*)&Qs[w * 16 + l16][32 + quad * 8];

  float m_[4], l_[4];
  frag_cd o_[4];
#pragma unroll
  for (int r = 0; r < 4; ++r) { m_[r] = -1e30f; l_[r] = 0.f; }
#pragma unroll
  for (int n = 0; n < 4; ++n)
#pragma unroll
    for (int r = 0; r < 4; ++r) o_[n][r] = 0.f;

  for (int kt = 0; kt < LL / 64; ++kt) {
    __syncthreads();
    for (int i = tid; i < 512; i += 256) {
      const int r = i >> 3, seg = i & 7;
      *(uint4*)&Ks[r][seg * 8] = *(const uint4*)&Kt[base + (size_t)(kt * 64 + r) * DD + seg * 8];
      uint4 vv = *(const uint4*)&V[base + (size_t)(kt * 64 + r) * DD + seg * 8];
      const bf16_t* vs = (const bf16_t*)&vv;
#pragma unroll
      for (int j = 0; j < 8; ++j) Vt[seg * 8 + j][r] = vs[j];  // transpose
    }
    __syncthreads();

    frag_cd s_[4];
#pragma unroll
    for (int n = 0; n < 4; ++n) {
      frag_ab b0 = *(const frag_ab*)&Ks[n * 16 + l16][quad * 8];
      frag_ab b1 = *(const frag_ab*)&Ks[n * 16 + l16][32 + quad * 8];
      frag_cd z; z[0] = z[1] = z[2] = z[3] = 0.f;
      z = __builtin_amdgcn_mfma_f32_16x16x32_bf16(aq0, b0, z, 0, 0, 0);
      s_[n] = __builtin_amdgcn_mfma_f32_16x16x32_bf16(aq1, b1, z, 0, 0, 0);
    }
#pragma unroll
    for (int n = 0; n < 4; ++n)
#pragma unroll
      for (int r = 0; r < 4; ++r) s_[n][r] *= 0.125f;  // 1/sqrt(DH)

#pragma unroll
    for (int r = 0; r < 4; ++r) {
      float mx = fmaxf(fmaxf(s_[0][r], s_[1][r]), fmaxf(s_[2][r], s_[3][r]));
#pragma unroll
      for (int m = 8; m > 0; m >>= 1) mx = fmaxf(mx, __shfl_xor(mx, m));
      const float newm = fmaxf(m_[r], mx);
      const float alpha = __expf(m_[r] - newm);
      float p0 = __expf(s_[0][r] - newm), p1 = __expf(s_[1][r] - newm);
      float p2 = __expf(s_[2][r] - newm), p3 = __expf(s_[3][r] - newm);
      float rs = p0 + p1 + p2 + p3;
#pragma unroll
      for (int m = 8; m > 0; m >>= 1) rs += __shfl_xor(rs, m);
      l_[r] = l_[r] * alpha + rs;
      m_[r] = newm;
#pragma unroll
      for (int n = 0; n < 4; ++n) o_[n][r] *= alpha;
      const int prow = w * 16 + quad * 4 + r;
      Ps[prow][0 * 16 + l16] = f2b(p0);
      Ps[prow][1 * 16 + l16] = f2b(p1);
      Ps[prow][2 * 16 + l16] = f2b(p2);
      Ps[prow][3 * 16 + l16] = f2b(p3);
    }

    frag_ab ap0 = *(const frag_ab*)&Ps[w * 16 + l16][quad * 8];
    frag_ab ap1 = *(const frag_ab*)&Ps[w * 16 + l16][32 + quad * 8];
#pragma unroll
    for (int n = 0; n < 4; ++n) {
      frag_ab bv0 = *(const frag_ab*)&Vt[n * 16 + l16][quad * 8];
      frag_ab bv1 = *(const frag_ab*)&Vt[n * 16 + l16][32 + quad * 8];
      o_[n] = __builtin_amdgcn_mfma_f32_16x16x32_bf16(ap0, bv0, o_[n], 0, 0, 0);
      o_[n] = __builtin_amdgcn_mfma_f32_16x16x32_bf16(ap1, bv1, o_[n], 0, 0, 0);
    }
  }

#pragma unroll
  for (int n = 0; n < 4; ++n)
#pragma unroll
    for (int r = 0; r < 4; ++r) {
      const float v = o_[n][r] / l_[r];
      O[base + (size_t)(q0 + w * 16 + quad * 4 + r) * DD + n * 16 + l16] = f2b(v);
    }
}

// layernorm(hidden + X) * gamma + beta -> FP32 out
__global__ __launch_bounds__(256) void ln_kernel(const float* __restrict__ hidden,
                                                 const float* __restrict__ x0,
                                                 const float* __restrict__ gamma,
                                                 const float* __restrict__ beta,
                                                 float* __restrict__ out) {
  const int row = blockIdx.x;
  const int tid = threadIdx.x;
  __shared__ float red1[4], red2[4];
  float v[4];
  float s1 = 0.f, s2 = 0.f;
#pragma unroll
  for (int s = 0; s < 4; ++s) {
    const int c = tid + s * 256;
    const float x = hidden[(size_t)row * DD + c] + x0[(size_t)row * DD + c];
    v[s] = x; s1 += x; s2 += x * x;
  }
  s1 = waveSum(s1); s2 = waveSum(s2);
  if ((tid & 63) == 0) { red1[tid >> 6] = s1; red2[tid >> 6] = s2; }
  __syncthreads();
  const float t1 = red1[0] + red1[1] + red1[2] + red1[3];
  const float t2 = red2[0] + red2[1] + red2[2] + red2[3];
  const float mu = t1 * (1.f / DD);
  const float var = t2 * (1.f / DD) - mu * mu;
  const float inv = rsqrtf(var + 1e-12f);
#pragma unroll
  for (int s = 0; s < 4; ++s) {
    const int c = tid + s * 256;
    out[(size_t)row * DD + c] = (v[s] - mu) * inv * gamma[c] + beta[c];
  }
}

// ---------------------------------------------------------------------------
extern "C" void kernel_launch(void* const* d_in, const int* in_sizes, int n_in,
                              void* d_out, int out_size, void* d_ws, size_t ws_size,
                              hipStream_t stream) {
  const float* X    = (const float*)d_in[0];
  const float* Wq   = (const float*)d_in[1];
  const float* bq   = (const float*)d_in[2];
  const float* Wk   = (const float*)d_in[3];
  const float* bk   = (const float*)d_in[4];
  const float* Wv   = (const float*)d_in[5];
  const float* bv   = (const float*)d_in[6];
  const float* Wd   = (const float*)d_in[7];
  const float* bd   = (const float*)d_in[8];
  const float* gam  = (const float*)d_in[9];
  const float* bet  = (const float*)d_in[10];
  const float* delt = (const float*)d_in[11];
  const float* beul = (const float*)d_in[12];
  const float* lsc  = (const float*)d_in[13];
  float* out = (float*)d_out;

  char* w = (char*)d_ws;
  const size_t MB = 1024ull * 1024ull;
  bf16_t* Xb  = (bf16_t*)(w + 0 * MB);    // 8MB
  bf16_t* Wqb = (bf16_t*)(w + 8 * MB);    // 2MB
  bf16_t* Wkb = (bf16_t*)(w + 10 * MB);   // 2MB
  bf16_t* Wvb = (bf16_t*)(w + 12 * MB);   // 2MB
  bf16_t* Wdb = (bf16_t*)(w + 14 * MB);   // 2MB
  bf16_t* qb  = (bf16_t*)(w + 16 * MB);   // 8MB  (dead after g2)
  bf16_t* kb  = (bf16_t*)(w + 24 * MB);   // 8MB  (dead after g3)
  bf16_t* vb  = (bf16_t*)(w + 32 * MB);   // 8MB
  bf16_t* qs  = (bf16_t*)(w + 40 * MB);   // 8MB  euler in-place
  bf16_t* ks  = (bf16_t*)(w + 48 * MB);   // 8MB
  bf16_t* Pq  = (bf16_t*)(w + 56 * MB);   // 4MB
  bf16_t* Pk  = (bf16_t*)(w + 60 * MB);   // 4MB
  bf16_t* ctx = (bf16_t*)(w + 64 * MB);   // 8MB
  float*  hid = (float*)(w + 16 * MB);    // 16MB, overlays dead qb/kb
  float*  xmean  = (float*)(w + 72 * MB);           // 8KB
  float*  scores = (float*)(w + 72 * MB + 16384);   // 16KB [t][b][i]
  float*  bsum   = (float*)(w + 72 * MB + 32768);   // 16KB

  // 0) casts fp32 -> bf16
  cast_f2b<<<dim3(4096), 256, 0, stream>>>(X,  Xb,  BB * LL * DD / 4);
  cast_f2b<<<dim3(1024), 256, 0, stream>>>(Wq, Wqb, DD * DD / 4);
  cast_f2b<<<dim3(1024), 256, 0, stream>>>(Wk, Wkb, DD * DD / 4);
  cast_f2b<<<dim3(1024), 256, 0, stream>>>(Wv, Wvb, DD * DD / 4);
  cast_f2b<<<dim3(1024), 256, 0, stream>>>(Wd, Wdb, DD * DD / 4);

  // 1) QKV projections (bf16 out)
  GemmArgs g1 = {};
  g1.gb[0] = {Xb, Wqb, bq, nullptr, qb};
  g1.gb[1] = {Xb, Wkb, bk, nullptr, kb};
  g1.gb[2] = {Xb, Wvb, bv, nullptr, vb};
  gemm128<<<dim3(8, 32, 3), 256, 0, stream>>>(g1, BB * LL, DD, DD);

  // 2) scores via linearity (exact fp32)
  hipMemsetAsync(xmean, 0, BB * DD * sizeof(float), stream);
  xmean_kernel<<<dim3(4, 32, 2), 256, 0, stream>>>(X, xmean);
  scores_gemm<<<dim3(16), 256, 0, stream>>>(xmean, Wq, bq, Wk, bk, scores);

  // 3) neural sort P matrices
  bsum_kernel<<<dim3(4), 1024, 0, stream>>>(scores, bsum);
  p_kernel<<<dim3(1024, 4), 256, 0, stream>>>(scores, bsum, Pq, Pk);

  // 4) sorted q/k = q @ P^T per batch (bf16 out)
  GemmArgs g2 = {};
  g2.gb[0] = {qb,                   Pq,                   nullptr, nullptr, qs};
  g2.gb[1] = {qb + (size_t)LL * DD, Pq + (size_t)DD * DD, nullptr, nullptr, qs + (size_t)LL * DD};
  gemm128<<<dim3(8, 16, 2), 256, 0, stream>>>(g2, LL, DD, DD);
  GemmArgs g3 = {};
  g3.gb[0] = {kb,                   Pk,                   nullptr, nullptr, ks};
  g3.gb[1] = {kb + (size_t)LL * DD, Pk + (size_t)DD * DD, nullptr, nullptr, ks + (size_t)LL * DD};
  gemm128<<<dim3(8, 16, 2), 256, 0, stream>>>(g3, LL, DD, DD);

  // 5) euler transforms (in place, bf16)
  euler_kernel<<<dim3(8192), 256, 0, stream>>>(qs, delt, beul, lsc, 1);
  euler_kernel<<<dim3(8192), 256, 0, stream>>>(ks, delt, beul, lsc, 0);

  // 6) attention (MFMA flash)
  attn_kernel<<<dim3(LL / 64, HH, BB), 256, 0, stream>>>(qs, ks, vb, ctx);

  // 7) output projection (fp32 out into hid, overlays dead qb/kb)
  GemmArgs g4 = {};
  g4.gb[0] = {ctx, Wdb, bd, hid, nullptr};
  gemm128<<<dim3(8, 32, 1), 256, 0, stream>>>(g4, BB * LL, DD, DD);

  // 8) layernorm + residual -> fp32
  ln_kernel<<<dim3(BB * LL), 256, 0, stream>>>(hid, X, gam, bet, out);
}

// Round 12
// 423.959 us; speedup vs baseline: 24.2802x; 1.2666x over previous
//
#include <hip/hip_runtime.h>

// ---------------------------------------------------------------------------
// Euler Attention forward, MI355X gfx950 — ROUND 12.
// r11 counters: attn 213us, MfmaUtil 6.5%, 6.2e7 LDS conflict-cycles (~47% of
// kernel). Fixes: padded LDS (stride 72), V pre-transposed in global (kills
// 16-way transpose writes), fixed-offset softmax exp(s/8-12) (identical math,
// no max/sum wave reductions, no alpha rescale). gemm128 staging switched to
// global_load_lds width=16 (m97 ladder step, 517->874 TF on 4k GEMM).
// ---------------------------------------------------------------------------

typedef unsigned short bf16_t;
typedef short frag_ab __attribute__((ext_vector_type(8)));   // 8 bf16 = 4 VGPRs
typedef float frag_cd __attribute__((ext_vector_type(4)));   // 4 fp32 acc

#define BB 2
#define LL 2048
#define DD 1024
#define HH 16
#define DH 64

__device__ __forceinline__ float b2f(bf16_t u) {
  union { unsigned int i; float f; } c; c.i = ((unsigned int)u) << 16; return c.f;
}
__device__ __forceinline__ bf16_t f2b(float f) {
  union { float f; unsigned int i; } c; c.f = f;
  unsigned int r = c.i + 0x7fffu + ((c.i >> 16) & 1u);
  return (bf16_t)(r >> 16);
}
__device__ __forceinline__ float waveMax(float v) {
#pragma unroll
  for (int m = 32; m > 0; m >>= 1) v = fmaxf(v, __shfl_xor(v, m));
  return v;
}
__device__ __forceinline__ float waveSum(float v) {
#pragma unroll
  for (int m = 32; m > 0; m >>= 1) v += __shfl_xor(v, m);
  return v;
}

// async global->LDS, 16B per lane; lds base must be wave-uniform (lane*16 added by HW)
__device__ __forceinline__ void gll16(const bf16_t* g, bf16_t* l) {
  __builtin_amdgcn_global_load_lds(
      (const __attribute__((address_space(1))) void*)g,
      (__attribute__((address_space(3))) void*)l, 16, 0, 0);
}

// fp32 -> bf16 cast, 4 elems/thread
__global__ __launch_bounds__(256) void cast_f2b(const float* __restrict__ in,
                                                bf16_t* __restrict__ out, int n4) {
  const int i = blockIdx.x * 256 + threadIdx.x;
  if (i < n4) {
    float4 v = ((const float4*)in)[i];
    ushort4 o;
    o.x = f2b(v.x); o.y = f2b(v.y); o.z = f2b(v.z); o.w = f2b(v.w);
    ((ushort4*)out)[i] = o;
  }
}

// ---------------------------------------------------------------------------
// 128x128 tile MFMA GEMM, C = A * B^T (+bias), async LDS staging (m97 style)
// ---------------------------------------------------------------------------
struct GemmB { const bf16_t* A; const bf16_t* Bm; const float* bias; float* Cf; bf16_t* Cb; };
struct GemmArgs { GemmB gb[4]; };

__global__ __launch_bounds__(256) void gemm128(GemmArgs ga, int M, int N, int K) {
  const GemmB g = ga.gb[blockIdx.z];
  const int bm = blockIdx.y * 128, bn = blockIdx.x * 128;
  __shared__ bf16_t As[128][32];
  __shared__ bf16_t Bs[128][32];
  bf16_t* As_f = &As[0][0];
  bf16_t* Bs_f = &Bs[0][0];
  const int tid = threadIdx.x;
  const int lane = tid & 63, w = tid >> 6;
  const int quad = lane >> 4, l16 = lane & 15;
  const int wm = (w >> 1) * 64, wn = (w & 1) * 64;
  const int wbase = w << 9;               // wave-uniform LDS elem offset (w*512)

  frag_cd acc[4][4];
#pragma unroll
  for (int i = 0; i < 4; ++i)
#pragma unroll
    for (int j = 0; j < 4; ++j)
#pragma unroll
      for (int r = 0; r < 4; ++r) acc[i][j][r] = 0.f;

  // slot mapping: thread t stages LDS bytes [t*16, t*16+16): row t>>2, seg (t&3)*8
  const int r0 = tid >> 2, s0 = (tid & 3) * 8;
  const int r1 = (tid + 256) >> 2, s1 = ((tid + 256) & 3) * 8;
  const size_t aoff0 = (size_t)(bm + r0) * K + s0;
  const size_t aoff1 = (size_t)(bm + r1) * K + s1;
  const size_t boff0 = (size_t)(bn + r0) * K + s0;
  const size_t boff1 = (size_t)(bn + r1) * K + s1;

  for (int k0 = 0; k0 < K; k0 += 32) {
    __syncthreads();                       // prior iter's LDS reads done
    gll16(g.A + aoff0 + k0, As_f + wbase);
    gll16(g.A + aoff1 + k0, As_f + 2048 + wbase);
    gll16(g.Bm + boff0 + k0, Bs_f + wbase);
    gll16(g.Bm + boff1 + k0, Bs_f + 2048 + wbase);
    __syncthreads();                       // compiler drains vmcnt before barrier
    frag_ab af[4], bfr[4];
#pragma unroll
    for (int i = 0; i < 4; ++i) {
      af[i]  = *(const frag_ab*)&As[wm + i * 16 + l16][quad * 8];
      bfr[i] = *(const frag_ab*)&Bs[wn + i * 16 + l16][quad * 8];
    }
#pragma unroll
    for (int i = 0; i < 4; ++i)
#pragma unroll
      for (int j = 0; j < 4; ++j)
        acc[i][j] = __builtin_amdgcn_mfma_f32_16x16x32_bf16(af[i], bfr[j], acc[i][j], 0, 0, 0);
  }

#pragma unroll
  for (int i = 0; i < 4; ++i) {
#pragma unroll
    for (int r = 0; r < 4; ++r) {
      const int row = bm + wm + i * 16 + quad * 4 + r;
#pragma unroll
      for (int j = 0; j < 4; ++j) {
        const int col = bn + wn + j * 16 + l16;
        float v = acc[i][j][r];
        if (g.bias) v += g.bias[col];
        if (g.Cf) g.Cf[(size_t)row * N + col] = v;
        if (g.Cb) g.Cb[(size_t)row * N + col] = f2b(v);
      }
    }
  }
}

// xmean[b][d] = mean over L of X[b][l][d]
__global__ __launch_bounds__(256) void xmean_kernel(const float* __restrict__ X,
                                                    float* __restrict__ xmean) {
  const int d = blockIdx.x * 256 + threadIdx.x;
  const int b = blockIdx.z;
  const int l0 = blockIdx.y * 64;
  float s = 0.f;
  for (int l = l0; l < l0 + 64; ++l)
    s += X[((size_t)b * LL + l) * DD + d];
  atomicAdd(&xmean[b * DD + d], s * (1.f / (float)LL));
}

// scores[t][b][i] = xmean[b] . W_t[i] + bias_t[i]   (exact fp32)
__global__ __launch_bounds__(256) void scores_gemm(const float* __restrict__ xmean,
                                                   const float* __restrict__ Wq,
                                                   const float* __restrict__ bq,
                                                   const float* __restrict__ Wk,
                                                   const float* __restrict__ bk,
                                                   float* __restrict__ scores) {
  const int idx = blockIdx.x * 256 + threadIdx.x;
  const int t = idx >> 11, b = (idx >> 10) & 1, i = idx & 1023;
  const float* W = t ? Wk : Wq;
  const float* bias = t ? bk : bq;
  const float* xm = xmean + b * DD;
  float sum = 0.f;
  for (int j = 0; j < DD; j += 4) {
    float4 wv = *(const float4*)&W[(size_t)i * DD + j];
    sum += xm[j] * wv.x + xm[j + 1] * wv.y + xm[j + 2] * wv.z + xm[j + 3] * wv.w;
  }
  scores[idx] = sum + bias[i];
}

// Bsum[z][j] = sum_m |scores[z][j] - scores[z][m]|
__global__ __launch_bounds__(1024) void bsum_kernel(const float* __restrict__ scores,
                                                    float* __restrict__ bsum) {
  __shared__ float sc[DD];
  const int z = blockIdx.x, tid = threadIdx.x;
  sc[tid] = scores[z * DD + tid];
  __syncthreads();
  const float si = sc[tid];
  float s = 0.f;
  for (int j = 0; j < DD; ++j) s += fabsf(si - sc[j]);
  bsum[z * DD + tid] = s;
}

// P[z][i][j] = softmax_j( scores[z][j]*(1023-2i) - Bsum[z][j] )  -> bf16
__global__ __launch_bounds__(256) void p_kernel(const float* __restrict__ scores,
                                                const float* __restrict__ bsum,
                                                bf16_t* __restrict__ Pq,
                                                bf16_t* __restrict__ Pk) {
  const int i = blockIdx.x;
  const int z = blockIdx.y;
  const int t = z >> 1, b = z & 1;
  const float* sc = scores + z * DD;
  const float* bs = bsum + z * DD;
  const float scal = 1023.f - 2.f * (float)i;
  const int tid = threadIdx.x;
  __shared__ float redA[4], redB[4];

  float lg[4];
  float mx = -1e30f;
#pragma unroll
  for (int s = 0; s < 4; ++s) {
    const int j = tid + s * 256;
    lg[s] = sc[j] * scal - bs[j];
    mx = fmaxf(mx, lg[s]);
  }
  mx = waveMax(mx);
  if ((tid & 63) == 0) redA[tid >> 6] = mx;
  __syncthreads();
  const float M = fmaxf(fmaxf(redA[0], redA[1]), fmaxf(redA[2], redA[3]));
  float sum = 0.f;
#pragma unroll
  for (int s = 0; s < 4; ++s) {
    lg[s] = __expf(lg[s] - M);
    sum += lg[s];
  }
  sum = waveSum(sum);
  if ((tid & 63) == 0) redB[tid >> 6] = sum;
  __syncthreads();
  const float inv = 1.f / (redB[0] + redB[1] + redB[2] + redB[3]);
  bf16_t* P = (t ? Pk : Pq) + ((size_t)b << 20) + (size_t)i * DD;
#pragma unroll
  for (int s = 0; s < 4; ++s) P[tid + s * 256] = f2b(lg[s] * inv);
}

// euler transform: bf16 in-place, both q and k in one launch (blockIdx.y)
__global__ __launch_bounds__(256) void euler_kernel(bf16_t* __restrict__ qs,
                                                    bf16_t* __restrict__ ks,
                                                    const float* __restrict__ delta,
                                                    const float* __restrict__ beul,
                                                    const float* __restrict__ lsc) {
  const int isq = (blockIdx.y == 0);
  bf16_t* buf = isq ? qs : ks;
  const int idx = blockIdx.x * 256 + threadIdx.x;
  const int c = idx & 511;
  const size_t n = idx >> 9;
  const float r = b2f(buf[n * DD + 2 * c]);
  const float p = b2f(buf[n * DD + 2 * c + 1]);
  float lam = sqrtf(r * r + p * p + 1e-6f);
  float th = atan2f(p, r) * delta[c];
  if (isq) th += beul[c];
  lam *= __expf(fminf(fmaxf(lsc[c], -5.f), 5.f));
  float sn, cs;
  __sincosf(th, &sn, &cs);
  buf[n * DD + 2 * c]     = f2b(lam * cs);
  buf[n * DD + 2 * c + 1] = f2b(lam * sn);
}

// V transpose: vb[(b*L + l)][dcol] -> vbT[(b*DD + dcol)][l]
__global__ __launch_bounds__(256) void transpose_v(const bf16_t* __restrict__ vb,
                                                   bf16_t* __restrict__ vbT) {
  __shared__ bf16_t T[64][72];
  const int l0 = blockIdx.x * 64, d0 = blockIdx.y * 64, b = blockIdx.z;
  const int tid = threadIdx.x;
  for (int i = tid; i < 512; i += 256) {
    const int r = i >> 3, seg = i & 7;
    uint4 v = *(const uint4*)&vb[((size_t)b * LL + l0 + r) * DD + d0 + seg * 8];
    const bf16_t* vs = (const bf16_t*)&v;
#pragma unroll
    for (int j = 0; j < 8; ++j) T[seg * 8 + j][r] = vs[j];
  }
  __syncthreads();
  for (int i = tid; i < 512; i += 256) {
    const int r = i >> 3, seg = i & 7;
    *(uint4*)&vbT[((size_t)b * DD + d0 + r) * LL + l0 + seg * 8] =
        *(const uint4*)&T[r][seg * 8];
  }
}

// ---------------------------------------------------------------------------
// Flash attention v2: padded LDS, V^T staged from global, fixed-offset exp
// (P = exp(s/8 - 12); mathematically identical to softmax, no max tracking).
// ---------------------------------------------------------------------------
__global__ __launch_bounds__(256) void attn_kernel(const bf16_t* __restrict__ Q,
                                                   const bf16_t* __restrict__ Kt,
                                                   const bf16_t* __restrict__ VT,
                                                   bf16_t* __restrict__ O) {
  const int b = blockIdx.z, h = blockIdx.y;
  const int q0 = blockIdx.x * 64;
  const int tid = threadIdx.x, w = tid >> 6, lane = tid & 63;
  const int quad = lane >> 4, l16 = lane & 15;
  __shared__ bf16_t Ks[64][72], Vs[64][72], Ps[64][72];
  const size_t base = ((size_t)b * LL) * DD + (size_t)h * DH;
  const size_t vtb = (size_t)(b * DD + h * DH) * LL;     // V^T row (b,dcol), col l

  // load Q fragments via Ps as scratch
  for (int i = tid; i < 512; i += 256) {
    const int r = i >> 3, seg = i & 7;
    *(uint4*)&Ps[r][seg * 8] = *(const uint4*)&Q[base + (size_t)(q0 + r) * DD + seg * 8];
  }
  __syncthreads();
  frag_ab aq0 = *(const frag_ab*)&Ps[w * 16 + l16][quad * 8];
  frag_ab aq1 = *(const frag_ab*)&Ps[w * 16 + l16][32 + quad * 8];

  float l_[4] = {0.f, 0.f, 0.f, 0.f};
  frag_cd o_[4];
#pragma unroll
  for (int n = 0; n < 4; ++n)
#pragma unroll
    for (int r = 0; r < 4; ++r) o_[n][r] = 0.f;

  for (int kt = 0; kt < LL / 64; ++kt) {
    __syncthreads();
    for (int i = tid; i < 512; i += 256) {
      const int r = i >> 3, seg = i & 7;
      *(uint4*)&Ks[r][seg * 8] = *(const uint4*)&Kt[base + (size_t)(kt * 64 + r) * DD + seg * 8];
      *(uint4*)&Vs[r][seg * 8] = *(const uint4*)&VT[vtb + (size_t)r * LL + kt * 64 + seg * 8];
    }
    __syncthreads();

    // S = Q K^T (16x64 per wave)
    frag_cd s_[4];
#pragma unroll
    for (int n = 0; n < 4; ++n) {
      frag_ab b0 = *(const frag_ab*)&Ks[n * 16 + l16][quad * 8];
      frag_ab b1 = *(const frag_ab*)&Ks[n * 16 + l16][32 + quad * 8];
      frag_cd z; z[0] = z[1] = z[2] = z[3] = 0.f;
      z = __builtin_amdgcn_mfma_f32_16x16x32_bf16(aq0, b0, z, 0, 0, 0);
      s_[n] = __builtin_amdgcn_mfma_f32_16x16x32_bf16(aq1, b1, z, 0, 0, 0);
    }

    // P = exp(s/8 - 12): row-independent offset == exact softmax after O/l
#pragma unroll
    for (int n = 0; n < 4; ++n)
#pragma unroll
      for (int r = 0; r < 4; ++r) {
        const float p = __expf(s_[n][r] * 0.125f - 12.f);
        l_[r] += p;
        Ps[w * 16 + quad * 4 + r][n * 16 + l16] = f2b(p);
      }

    // O += P V   (A from Ps, B from Vs; wave-local rows, no barrier needed)
    frag_ab ap0 = *(const frag_ab*)&Ps[w * 16 + l16][quad * 8];
    frag_ab ap1 = *(const frag_ab*)&Ps[w * 16 + l16][32 + quad * 8];
#pragma unroll
    for (int n = 0; n < 4; ++n) {
      frag_ab bv0 = *(const frag_ab*)&Vs[n * 16 + l16][quad * 8];
      frag_ab bv1 = *(const frag_ab*)&Vs[n * 16 + l16][32 + quad * 8];
      o_[n] = __builtin_amdgcn_mfma_f32_16x16x32_bf16(ap0, bv0, o_[n], 0, 0, 0);
      o_[n] = __builtin_amdgcn_mfma_f32_16x16x32_bf16(ap1, bv1, o_[n], 0, 0, 0);
    }
  }

  // row-sum reduction across l16 (once, 4 shuffles)
#pragma unroll
  for (int r = 0; r < 4; ++r) {
#pragma unroll
    for (int m = 8; m > 0; m >>= 1) l_[r] += __shfl_xor(l_[r], m);
  }
#pragma unroll
  for (int n = 0; n < 4; ++n)
#pragma unroll
    for (int r = 0; r < 4; ++r) {
      const float v = o_[n][r] / l_[r];
      O[base + (size_t)(q0 + w * 16 + quad * 4 + r) * DD + n * 16 + l16] = f2b(v);
    }
}

// layernorm(hidden + X) * gamma + beta -> FP32 out
__global__ __launch_bounds__(256) void ln_kernel(const float* __restrict__ hidden,
                                                 const float* __restrict__ x0,
                                                 const float* __restrict__ gamma,
                                                 const float* __restrict__ beta,
                                                 float* __restrict__ out) {
  const int row = blockIdx.x;
  const int tid = threadIdx.x;
  __shared__ float red1[4], red2[4];
  float v[4];
  float s1 = 0.f, s2 = 0.f;
#pragma unroll
  for (int s = 0; s < 4; ++s) {
    const int c = tid + s * 256;
    const float x = hidden[(size_t)row * DD + c] + x0[(size_t)row * DD + c];
    v[s] = x; s1 += x; s2 += x * x;
  }
  s1 = waveSum(s1); s2 = waveSum(s2);
  if ((tid & 63) == 0) { red1[tid >> 6] = s1; red2[tid >> 6] = s2; }
  __syncthreads();
  const float t1 = red1[0] + red1[1] + red1[2] + red1[3];
  const float t2 = red2[0] + red2[1] + red2[2] + red2[3];
  const float mu = t1 * (1.f / DD);
  const float var = t2 * (1.f / DD) - mu * mu;
  const float inv = rsqrtf(var + 1e-12f);
#pragma unroll
  for (int s = 0; s < 4; ++s) {
    const int c = tid + s * 256;
    out[(size_t)row * DD + c] = (v[s] - mu) * inv * gamma[c] + beta[c];
  }
}

// ---------------------------------------------------------------------------
extern "C" void kernel_launch(void* const* d_in, const int* in_sizes, int n_in,
                              void* d_out, int out_size, void* d_ws, size_t ws_size,
                              hipStream_t stream) {
  const float* X    = (const float*)d_in[0];
  const float* Wq   = (const float*)d_in[1];
  const float* bq   = (const float*)d_in[2];
  const float* Wk   = (const float*)d_in[3];
  const float* bk   = (const float*)d_in[4];
  const float* Wv   = (const float*)d_in[5];
  const float* bv   = (const float*)d_in[6];
  const float* Wd   = (const float*)d_in[7];
  const float* bd   = (const float*)d_in[8];
  const float* gam  = (const float*)d_in[9];
  const float* bet  = (const float*)d_in[10];
  const float* delt = (const float*)d_in[11];
  const float* beul = (const float*)d_in[12];
  const float* lsc  = (const float*)d_in[13];
  float* out = (float*)d_out;

  char* w = (char*)d_ws;
  const size_t MB = 1024ull * 1024ull;
  bf16_t* Xb  = (bf16_t*)(w + 0 * MB);    // 8MB
  bf16_t* Wqb = (bf16_t*)(w + 8 * MB);    // 2MB
  bf16_t* Wkb = (bf16_t*)(w + 10 * MB);   // 2MB
  bf16_t* Wvb = (bf16_t*)(w + 12 * MB);   // 2MB
  bf16_t* Wdb = (bf16_t*)(w + 14 * MB);   // 2MB
  bf16_t* qb  = (bf16_t*)(w + 16 * MB);   // 8MB  (dead after g2)
  bf16_t* kb  = (bf16_t*)(w + 24 * MB);   // 8MB  (dead after g3)
  bf16_t* vb  = (bf16_t*)(w + 32 * MB);   // 8MB  (dead after transpose)
  bf16_t* qs  = (bf16_t*)(w + 40 * MB);   // 8MB  euler in-place
  bf16_t* ks  = (bf16_t*)(w + 48 * MB);   // 8MB
  bf16_t* Pq  = (bf16_t*)(w + 56 * MB);   // 4MB
  bf16_t* Pk  = (bf16_t*)(w + 60 * MB);   // 4MB
  bf16_t* ctx = (bf16_t*)(w + 64 * MB);   // 8MB
  bf16_t* vbT = (bf16_t*)(w + 16 * MB);   // 8MB, overlays dead qb
  float*  hid = (float*)(w + 16 * MB);    // 16MB, overlays vbT/kb after attn
  float*  xmean  = (float*)(w + 72 * MB);           // 8KB
  float*  scores = (float*)(w + 72 * MB + 16384);   // 16KB
  float*  bsum   = (float*)(w + 72 * MB + 32768);   // 16KB

  // 0) casts fp32 -> bf16
  cast_f2b<<<dim3(4096), 256, 0, stream>>>(X,  Xb,  BB * LL * DD / 4);
  cast_f2b<<<dim3(1024), 256, 0, stream>>>(Wq, Wqb, DD * DD / 4);
  cast_f2b<<<dim3(1024), 256, 0, stream>>>(Wk, Wkb, DD * DD / 4);
  cast_f2b<<<dim3(1024), 256, 0, stream>>>(Wv, Wvb, DD * DD / 4);
  cast_f2b<<<dim3(1024), 256, 0, stream>>>(Wd, Wdb, DD * DD / 4);

  // 1) QKV projections
  GemmArgs g1 = {};
  g1.gb[0] = {Xb, Wqb, bq, nullptr, qb};
  g1.gb[1] = {Xb, Wkb, bk, nullptr, kb};
  g1.gb[2] = {Xb, Wvb, bv, nullptr, vb};
  gemm128<<<dim3(8, 32, 3), 256, 0, stream>>>(g1, BB * LL, DD, DD);

  // 2) scores via linearity (exact fp32)
  hipMemsetAsync(xmean, 0, BB * DD * sizeof(float), stream);
  xmean_kernel<<<dim3(4, 32, 2), 256, 0, stream>>>(X, xmean);
  scores_gemm<<<dim3(16), 256, 0, stream>>>(xmean, Wq, bq, Wk, bk, scores);

  // 3) neural sort P matrices
  bsum_kernel<<<dim3(4), 1024, 0, stream>>>(scores, bsum);
  p_kernel<<<dim3(1024, 4), 256, 0, stream>>>(scores, bsum, Pq, Pk);

  // 4) sorted q/k (bf16 out)
  GemmArgs g2 = {};
  g2.gb[0] = {qb,                   Pq,                   nullptr, nullptr, qs};
  g2.gb[1] = {qb + (size_t)LL * DD, Pq + (size_t)DD * DD, nullptr, nullptr, qs + (size_t)LL * DD};
  gemm128<<<dim3(8, 16, 2), 256, 0, stream>>>(g2, LL, DD, DD);
  GemmArgs g3 = {};
  g3.gb[0] = {kb,                   Pk,                   nullptr, nullptr, ks};
  g3.gb[1] = {kb + (size_t)LL * DD, Pk + (size_t)DD * DD, nullptr, nullptr, ks + (size_t)LL * DD};
  gemm128<<<dim3(8, 16, 2), 256, 0, stream>>>(g3, LL, DD, DD);

  // 4b) V transpose into dead qb space
  transpose_v<<<dim3(32, 16, 2), 256, 0, stream>>>(vb, vbT);

  // 5) euler transforms (merged)
  euler_kernel<<<dim3(8192, 2), 256, 0, stream>>>(qs, ks, delt, beul, lsc);

  // 6) attention (MFMA flash, V^T staging)
  attn_kernel<<<dim3(LL / 64, HH, BB), 256, 0, stream>>>(qs, ks, vbT, ctx);

  // 7) output projection (fp32 into hid, overlays [16,32))
  GemmArgs g4 = {};
  g4.gb[0] = {ctx, Wdb, bd, hid, nullptr};
  gemm128<<<dim3(8, 32, 1), 256, 0, stream>>>(g4, BB * LL, DD, DD);

  // 8) layernorm + residual -> fp32
  ln_kernel<<<dim3(BB * LL), 256, 0, stream>>>(hid, X, gam, bet, out);
}

// Round 13
// 419.032 us; speedup vs baseline: 24.5656x; 1.0118x over previous
//
#include <hip/hip_runtime.h>

// ---------------------------------------------------------------------------
// Euler Attention forward, MI355X gfx950 — ROUND 13.
// r12: 424us. attn fixed (84us); remaining time is the GEMM chain + launches.
// Changes:
//  1) Algebra: q_sorted = X·(P·Wq)^T + P·bq  (same for k). GEMM flops
//     68.8 -> 43 GF, qb/kb buffers eliminated, g1/g2/g3 -> gW(z=4)+gS(z=6).
//  2) attn: XCD-aware block swizzle (all q-tiles of a head -> same XCD).
//  3) cast+transpose Wq/Wk fused; P·bias folded into gemm bias slots.
// ---------------------------------------------------------------------------

typedef unsigned short bf16_t;
typedef short frag_ab __attribute__((ext_vector_type(8)));   // 8 bf16 = 4 VGPRs
typedef float frag_cd __attribute__((ext_vector_type(4)));   // 4 fp32 acc

#define BB 2
#define LL 2048
#define DD 1024
#define HH 16
#define DH 64

__device__ __forceinline__ float b2f(bf16_t u) {
  union { unsigned int i; float f; } c; c.i = ((unsigned int)u) << 16; return c.f;
}
__device__ __forceinline__ bf16_t f2b(float f) {
  union { float f; unsigned int i; } c; c.f = f;
  unsigned int r = c.i + 0x7fffu + ((c.i >> 16) & 1u);
  return (bf16_t)(r >> 16);
}
__device__ __forceinline__ float waveMax(float v) {
#pragma unroll
  for (int m = 32; m > 0; m >>= 1) v = fmaxf(v, __shfl_xor(v, m));
  return v;
}
__device__ __forceinline__ float waveSum(float v) {
#pragma unroll
  for (int m = 32; m > 0; m >>= 1) v += __shfl_xor(v, m);
  return v;
}

// async global->LDS, 16B/lane; lds base wave-uniform (HW adds lane*16)
__device__ __forceinline__ void gll16(const bf16_t* g, bf16_t* l) {
  __builtin_amdgcn_global_load_lds(
      (const __attribute__((address_space(1))) void*)g,
      (__attribute__((address_space(3))) void*)l, 16, 0, 0);
}

// fp32 -> bf16 cast, 4 elems/thread
__global__ __launch_bounds__(256) void cast_f2b(const float* __restrict__ in,
                                                bf16_t* __restrict__ out, int n4) {
  const int i = blockIdx.x * 256 + threadIdx.x;
  if (i < n4) {
    float4 v = ((const float4*)in)[i];
    ushort4 o;
    o.x = f2b(v.x); o.y = f2b(v.y); o.z = f2b(v.z); o.w = f2b(v.w);
    ((ushort4*)out)[i] = o;
  }
}

// cast + transpose 1024x1024 fp32 W -> bf16 W^T (z: 0=Wq, 1=Wk)
__global__ __launch_bounds__(256) void cast_transpose_w(const float* __restrict__ Wq,
                                                        const float* __restrict__ Wk,
                                                        bf16_t* __restrict__ WqT,
                                                        bf16_t* __restrict__ WkT) {
  const float* W = blockIdx.z ? Wk : Wq;
  bf16_t* WT = blockIdx.z ? WkT : WqT;
  __shared__ bf16_t T[64][72];
  const int i0 = blockIdx.x * 64, m0 = blockIdx.y * 64;
  const int tid = threadIdx.x;
#pragma unroll
  for (int it = 0; it < 4; ++it) {
    const int idx = tid + it * 256;          // 0..1023
    const int r = idx >> 4, c4 = (idx & 15) * 4;
    float4 v = *(const float4*)&W[(size_t)(i0 + r) * DD + m0 + c4];
    T[c4 + 0][r] = f2b(v.x);
    T[c4 + 1][r] = f2b(v.y);
    T[c4 + 2][r] = f2b(v.z);
    T[c4 + 3][r] = f2b(v.w);
  }
  __syncthreads();
#pragma unroll
  for (int it = 0; it < 2; ++it) {
    const int idx = tid + it * 256;          // 0..511
    const int r = idx >> 3, seg = idx & 7;
    *(uint4*)&WT[(size_t)(m0 + r) * DD + i0 + seg * 8] = *(const uint4*)&T[r][seg * 8];
  }
}

// ---------------------------------------------------------------------------
// 128x128 tile MFMA GEMM, C = A * B^T (+bias), async LDS staging
// ---------------------------------------------------------------------------
struct GemmB { const bf16_t* A; const bf16_t* Bm; const float* bias; float* Cf; bf16_t* Cb; };
struct GemmArgs { GemmB gb[6]; };

__global__ __launch_bounds__(256) void gemm128(GemmArgs ga, int M, int N, int K) {
  const GemmB g = ga.gb[blockIdx.z];
  const int bm = blockIdx.y * 128, bn = blockIdx.x * 128;
  __shared__ bf16_t As[128][32];
  __shared__ bf16_t Bs[128][32];
  bf16_t* As_f = &As[0][0];
  bf16_t* Bs_f = &Bs[0][0];
  const int tid = threadIdx.x;
  const int lane = tid & 63, w = tid >> 6;
  const int quad = lane >> 4, l16 = lane & 15;
  const int wm = (w >> 1) * 64, wn = (w & 1) * 64;
  const int wbase = w << 9;

  frag_cd acc[4][4];
#pragma unroll
  for (int i = 0; i < 4; ++i)
#pragma unroll
    for (int j = 0; j < 4; ++j)
#pragma unroll
      for (int r = 0; r < 4; ++r) acc[i][j][r] = 0.f;

  const int r0 = tid >> 2, s0 = (tid & 3) * 8;
  const int r1 = (tid + 256) >> 2, s1 = ((tid + 256) & 3) * 8;
  const size_t aoff0 = (size_t)(bm + r0) * K + s0;
  const size_t aoff1 = (size_t)(bm + r1) * K + s1;
  const size_t boff0 = (size_t)(bn + r0) * K + s0;
  const size_t boff1 = (size_t)(bn + r1) * K + s1;

  for (int k0 = 0; k0 < K; k0 += 32) {
    __syncthreads();
    gll16(g.A + aoff0 + k0, As_f + wbase);
    gll16(g.A + aoff1 + k0, As_f + 2048 + wbase);
    gll16(g.Bm + boff0 + k0, Bs_f + wbase);
    gll16(g.Bm + boff1 + k0, Bs_f + 2048 + wbase);
    __syncthreads();
    frag_ab af[4], bfr[4];
#pragma unroll
    for (int i = 0; i < 4; ++i) {
      af[i]  = *(const frag_ab*)&As[wm + i * 16 + l16][quad * 8];
      bfr[i] = *(const frag_ab*)&Bs[wn + i * 16 + l16][quad * 8];
    }
#pragma unroll
    for (int i = 0; i < 4; ++i)
#pragma unroll
      for (int j = 0; j < 4; ++j)
        acc[i][j] = __builtin_amdgcn_mfma_f32_16x16x32_bf16(af[i], bfr[j], acc[i][j], 0, 0, 0);
  }

#pragma unroll
  for (int i = 0; i < 4; ++i) {
#pragma unroll
    for (int r = 0; r < 4; ++r) {
      const int row = bm + wm + i * 16 + quad * 4 + r;
#pragma unroll
      for (int j = 0; j < 4; ++j) {
        const int col = bn + wn + j * 16 + l16;
        float v = acc[i][j][r];
        if (g.bias) v += g.bias[col];
        if (g.Cf) g.Cf[(size_t)row * N + col] = v;
        if (g.Cb) g.Cb[(size_t)row * N + col] = f2b(v);
      }
    }
  }
}

// xmean[b][d] = mean over L of X[b][l][d]
__global__ __launch_bounds__(256) void xmean_kernel(const float* __restrict__ X,
                                                    float* __restrict__ xmean) {
  const int d = blockIdx.x * 256 + threadIdx.x;
  const int b = blockIdx.z;
  const int l0 = blockIdx.y * 64;
  float s = 0.f;
  for (int l = l0; l < l0 + 64; ++l)
    s += X[((size_t)b * LL + l) * DD + d];
  atomicAdd(&xmean[b * DD + d], s * (1.f / (float)LL));
}

// scores[t][b][i] = xmean[b] . W_t[i] + bias_t[i]   (exact fp32)
__global__ __launch_bounds__(256) void scores_gemm(const float* __restrict__ xmean,
                                                   const float* __restrict__ Wq,
                                                   const float* __restrict__ bq,
                                                   const float* __restrict__ Wk,
                                                   const float* __restrict__ bk,
                                                   float* __restrict__ scores) {
  const int idx = blockIdx.x * 256 + threadIdx.x;
  const int t = idx >> 11, b = (idx >> 10) & 1, i = idx & 1023;
  const float* W = t ? Wk : Wq;
  const float* bias = t ? bk : bq;
  const float* xm = xmean + b * DD;
  float sum = 0.f;
  for (int j = 0; j < DD; j += 4) {
    float4 wv = *(const float4*)&W[(size_t)i * DD + j];
    sum += xm[j] * wv.x + xm[j + 1] * wv.y + xm[j + 2] * wv.z + xm[j + 3] * wv.w;
  }
  scores[idx] = sum + bias[i];
}

// Bsum[z][j] = sum_m |scores[z][j] - scores[z][m]|
__global__ __launch_bounds__(1024) void bsum_kernel(const float* __restrict__ scores,
                                                    float* __restrict__ bsum) {
  __shared__ float sc[DD];
  const int z = blockIdx.x, tid = threadIdx.x;
  sc[tid] = scores[z * DD + tid];
  __syncthreads();
  const float si = sc[tid];
  float s = 0.f;
  for (int j = 0; j < DD; ++j) s += fabsf(si - sc[j]);
  bsum[z * DD + tid] = s;
}

// P[z][i][j] = softmax_j( scores[z][j]*(1023-2i) - Bsum[z][j] )  -> bf16
__global__ __launch_bounds__(256) void p_kernel(const float* __restrict__ scores,
                                                const float* __restrict__ bsum,
                                                bf16_t* __restrict__ Pq,
                                                bf16_t* __restrict__ Pk) {
  const int i = blockIdx.x;
  const int z = blockIdx.y;
  const int t = z >> 1, b = z & 1;
  const float* sc = scores + z * DD;
  const float* bs = bsum + z * DD;
  const float scal = 1023.f - 2.f * (float)i;
  const int tid = threadIdx.x;
  __shared__ float redA[4], redB[4];

  float lg[4];
  float mx = -1e30f;
#pragma unroll
  for (int s = 0; s < 4; ++s) {
    const int j = tid + s * 256;
    lg[s] = sc[j] * scal - bs[j];
    mx = fmaxf(mx, lg[s]);
  }
  mx = waveMax(mx);
  if ((tid & 63) == 0) redA[tid >> 6] = mx;
  __syncthreads();
  const float M = fmaxf(fmaxf(redA[0], redA[1]), fmaxf(redA[2], redA[3]));
  float sum = 0.f;
#pragma unroll
  for (int s = 0; s < 4; ++s) {
    lg[s] = __expf(lg[s] - M);
    sum += lg[s];
  }
  sum = waveSum(sum);
  if ((tid & 63) == 0) redB[tid >> 6] = sum;
  __syncthreads();
  const float inv = 1.f / (redB[0] + redB[1] + redB[2] + redB[3]);
  bf16_t* P = (t ? Pk : Pq) + ((size_t)b << 20) + (size_t)i * DD;
#pragma unroll
  for (int s = 0; s < 4; ++s) P[tid + s * 256] = f2b(lg[s] * inv);
}

// bias'[t][b][j] = sum_i P_t[b][j][i] * bias_t[i]   (fp32 out)
__global__ __launch_bounds__(256) void pbias_kernel(const bf16_t* __restrict__ Pq,
                                                    const bf16_t* __restrict__ Pk,
                                                    const float* __restrict__ bq,
                                                    const float* __restrict__ bk,
                                                    float* __restrict__ bias4) {
  const int idx = blockIdx.x * 256 + threadIdx.x;   // 0..4095
  const int t = idx >> 11, b = (idx >> 10) & 1, j = idx & 1023;
  const bf16_t* P = (t ? Pk : Pq) + ((size_t)b << 20) + (size_t)j * DD;
  const float* bias = t ? bk : bq;
  float sum = 0.f;
  for (int i = 0; i < DD; i += 8) {
    uint4 pv = *(const uint4*)&P[i];
    const bf16_t* ps = (const bf16_t*)&pv;
#pragma unroll
    for (int u = 0; u < 8; ++u) sum += b2f(ps[u]) * bias[i + u];
  }
  bias4[idx] = sum;
}

// euler transform: bf16 in-place, q and k in one launch
__global__ __launch_bounds__(256) void euler_kernel(bf16_t* __restrict__ qs,
                                                    bf16_t* __restrict__ ks,
                                                    const float* __restrict__ delta,
                                                    const float* __restrict__ beul,
                                                    const float* __restrict__ lsc) {
  const int isq = (blockIdx.y == 0);
  bf16_t* buf = isq ? qs : ks;
  const int idx = blockIdx.x * 256 + threadIdx.x;
  const int c = idx & 511;
  const size_t n = idx >> 9;
  const float r = b2f(buf[n * DD + 2 * c]);
  const float p = b2f(buf[n * DD + 2 * c + 1]);
  float lam = sqrtf(r * r + p * p + 1e-6f);
  float th = atan2f(p, r) * delta[c];
  if (isq) th += beul[c];
  lam *= __expf(fminf(fmaxf(lsc[c], -5.f), 5.f));
  float sn, cs;
  __sincosf(th, &sn, &cs);
  buf[n * DD + 2 * c]     = f2b(lam * cs);
  buf[n * DD + 2 * c + 1] = f2b(lam * sn);
}

// V transpose: vb[(b*L + l)][d] -> vbT[(b*DD + d)][l]
__global__ __launch_bounds__(256) void transpose_v(const bf16_t* __restrict__ vb,
                                                   bf16_t* __restrict__ vbT) {
  __shared__ bf16_t T[64][72];
  const int l0 = blockIdx.x * 64, d0 = blockIdx.y * 64, b = blockIdx.z;
  const int tid = threadIdx.x;
  for (int i = tid; i < 512; i += 256) {
    const int r = i >> 3, seg = i & 7;
    uint4 v = *(const uint4*)&vb[((size_t)b * LL + l0 + r) * DD + d0 + seg * 8];
    const bf16_t* vs = (const bf16_t*)&v;
#pragma unroll
    for (int j = 0; j < 8; ++j) T[seg * 8 + j][r] = vs[j];
  }
  __syncthreads();
  for (int i = tid; i < 512; i += 256) {
    const int r = i >> 3, seg = i & 7;
    *(uint4*)&vbT[((size_t)b * DD + d0 + r) * LL + l0 + seg * 8] =
        *(const uint4*)&T[r][seg * 8];
  }
}

// ---------------------------------------------------------------------------
// Flash attention: padded LDS, V^T staged, fixed-offset exp, XCD swizzle.
// 1-D grid of 1024; bid%8 constant per head-group -> same XCD (L2 locality).
// ---------------------------------------------------------------------------
__global__ __launch_bounds__(256) void attn_kernel(const bf16_t* __restrict__ Q,
                                                   const bf16_t* __restrict__ Kt,
                                                   const bf16_t* __restrict__ VT,
                                                   bf16_t* __restrict__ O) {
  const int bid = blockIdx.x;
  const int g = (bid & 7) + 8 * (bid >> 8);        // head-group 0..31
  const int qt = (bid >> 3) & 31;
  const int b = g >> 4, h = g & 15;
  const int q0 = qt * 64;
  const int tid = threadIdx.x, w = tid >> 6, lane = tid & 63;
  const int quad = lane >> 4, l16 = lane & 15;
  __shared__ bf16_t Ks[64][72], Vs[64][72], Ps[64][72];
  const size_t base = ((size_t)b * LL) * DD + (size_t)h * DH;
  const size_t vtb = (size_t)(b * DD + h * DH) * LL;

  for (int i = tid; i < 512; i += 256) {
    const int r = i >> 3, seg = i & 7;
    *(uint4*)&Ps[r][seg * 8] = *(const uint4*)&Q[base + (size_t)(q0 + r) * DD + seg * 8];
  }
  __syncthreads();
  frag_ab aq0 = *(const frag_ab*)&Ps[w * 16 + l16][quad * 8];
  frag_ab aq1 = *(const frag_ab*)&Ps[w * 16 + l16][32 + quad * 8];

  float l_[4] = {0.f, 0.f, 0.f, 0.f};
  frag_cd o_[4];
#pragma unroll
  for (int n = 0; n < 4; ++n)
#pragma unroll
    for (int r = 0; r < 4; ++r) o_[n][r] = 0.f;

  for (int kt = 0; kt < LL / 64; ++kt) {
    __syncthreads();
    for (int i = tid; i < 512; i += 256) {
      const int r = i >> 3, seg = i & 7;
      *(uint4*)&Ks[r][seg * 8] = *(const uint4*)&Kt[base + (size_t)(kt * 64 + r) * DD + seg * 8];
      *(uint4*)&Vs[r][seg * 8] = *(const uint4*)&VT[vtb + (size_t)r * LL + kt * 64 + seg * 8];
    }
    __syncthreads();

    frag_cd s_[4];
#pragma unroll
    for (int n = 0; n < 4; ++n) {
      frag_ab b0 = *(const frag_ab*)&Ks[n * 16 + l16][quad * 8];
      frag_ab b1 = *(const frag_ab*)&Ks[n * 16 + l16][32 + quad * 8];
      frag_cd z; z[0] = z[1] = z[2] = z[3] = 0.f;
      z = __builtin_amdgcn_mfma_f32_16x16x32_bf16(aq0, b0, z, 0, 0, 0);
      s_[n] = __builtin_amdgcn_mfma_f32_16x16x32_bf16(aq1, b1, z, 0, 0, 0);
    }

#pragma unroll
    for (int n = 0; n < 4; ++n)
#pragma unroll
      for (int r = 0; r < 4; ++r) {
        const float p = __expf(s_[n][r] * 0.125f - 12.f);
        l_[r] += p;
        Ps[w * 16 + quad * 4 + r][n * 16 + l16] = f2b(p);
      }

    frag_ab ap0 = *(const frag_ab*)&Ps[w * 16 + l16][quad * 8];
    frag_ab ap1 = *(const frag_ab*)&Ps[w * 16 + l16][32 + quad * 8];
#pragma unroll
    for (int n = 0; n < 4; ++n) {
      frag_ab bv0 = *(const frag_ab*)&Vs[n * 16 + l16][quad * 8];
      frag_ab bv1 = *(const frag_ab*)&Vs[n * 16 + l16][32 + quad * 8];
      o_[n] = __builtin_amdgcn_mfma_f32_16x16x32_bf16(ap0, bv0, o_[n], 0, 0, 0);
      o_[n] = __builtin_amdgcn_mfma_f32_16x16x32_bf16(ap1, bv1, o_[n], 0, 0, 0);
    }
  }

#pragma unroll
  for (int r = 0; r < 4; ++r) {
#pragma unroll
    for (int m = 8; m > 0; m >>= 1) l_[r] += __shfl_xor(l_[r], m);
  }
#pragma unroll
  for (int n = 0; n < 4; ++n)
#pragma unroll
    for (int r = 0; r < 4; ++r) {
      const float v = o_[n][r] / l_[r];
      O[base + (size_t)(q0 + w * 16 + quad * 4 + r) * DD + n * 16 + l16] = f2b(v);
    }
}

// layernorm(hidden + X) * gamma + beta -> FP32 out
__global__ __launch_bounds__(256) void ln_kernel(const float* __restrict__ hidden,
                                                 const float* __restrict__ x0,
                                                 const float* __restrict__ gamma,
                                                 const float* __restrict__ beta,
                                                 float* __restrict__ out) {
  const int row = blockIdx.x;
  const int tid = threadIdx.x;
  __shared__ float red1[4], red2[4];
  float v[4];
  float s1 = 0.f, s2 = 0.f;
#pragma unroll
  for (int s = 0; s < 4; ++s) {
    const int c = tid + s * 256;
    const float x = hidden[(size_t)row * DD + c] + x0[(size_t)row * DD + c];
    v[s] = x; s1 += x; s2 += x * x;
  }
  s1 = waveSum(s1); s2 = waveSum(s2);
  if ((tid & 63) == 0) { red1[tid >> 6] = s1; red2[tid >> 6] = s2; }
  __syncthreads();
  const float t1 = red1[0] + red1[1] + red1[2] + red1[3];
  const float t2 = red2[0] + red2[1] + red2[2] + red2[3];
  const float mu = t1 * (1.f / DD);
  const float var = t2 * (1.f / DD) - mu * mu;
  const float inv = rsqrtf(var + 1e-12f);
#pragma unroll
  for (int s = 0; s < 4; ++s) {
    const int c = tid + s * 256;
    out[(size_t)row * DD + c] = (v[s] - mu) * inv * gamma[c] + beta[c];
  }
}

// ---------------------------------------------------------------------------
extern "C" void kernel_launch(void* const* d_in, const int* in_sizes, int n_in,
                              void* d_out, int out_size, void* d_ws, size_t ws_size,
                              hipStream_t stream) {
  const float* X    = (const float*)d_in[0];
  const float* Wq   = (const float*)d_in[1];
  const float* bq   = (const float*)d_in[2];
  const float* Wk   = (const float*)d_in[3];
  const float* bk   = (const float*)d_in[4];
  const float* Wv   = (const float*)d_in[5];
  const float* bv   = (const float*)d_in[6];
  const float* Wd   = (const float*)d_in[7];
  const float* bd   = (const float*)d_in[8];
  const float* gam  = (const float*)d_in[9];
  const float* bet  = (const float*)d_in[10];
  const float* delt = (const float*)d_in[11];
  const float* beul = (const float*)d_in[12];
  const float* lsc  = (const float*)d_in[13];
  float* out = (float*)d_out;

  char* w = (char*)d_ws;
  const size_t MB = 1024ull * 1024ull;
  bf16_t* Xb  = (bf16_t*)(w + 0 * MB);    // 8MB
  bf16_t* Wvb = (bf16_t*)(w + 8 * MB);    // 2MB
  bf16_t* Wdb = (bf16_t*)(w + 10 * MB);   // 2MB
  bf16_t* WqT = (bf16_t*)(w + 12 * MB);   // 2MB
  bf16_t* WkT = (bf16_t*)(w + 14 * MB);   // 2MB
  bf16_t* Pq  = (bf16_t*)(w + 16 * MB);   // 4MB
  bf16_t* Pk  = (bf16_t*)(w + 20 * MB);   // 4MB
  bf16_t* Wp  = (bf16_t*)(w + 24 * MB);   // 8MB: W'q[2], W'k[2] (2MB each)
  bf16_t* vb  = (bf16_t*)(w + 32 * MB);   // 8MB  (dead after transpose_v)
  bf16_t* qs  = (bf16_t*)(w + 40 * MB);   // 8MB
  bf16_t* ks  = (bf16_t*)(w + 48 * MB);   // 8MB
  bf16_t* vbT = (bf16_t*)(w + 56 * MB);   // 8MB
  bf16_t* ctx = (bf16_t*)(w + 64 * MB);   // 8MB
  float*  hid = (float*)(w + 24 * MB);    // 16MB overlays Wp+vb (dead after attn)
  float*  xmean  = (float*)(w + 72 * MB);             // 8KB
  float*  scores = (float*)(w + 72 * MB + 16384);     // 16KB
  float*  bsum   = (float*)(w + 72 * MB + 32768);     // 16KB
  float*  bias4  = (float*)(w + 72 * MB + 49152);     // 16KB [t][b][j]

  const size_t WSZ = (size_t)DD * DD;     // 1M elems

  // 0) casts + W transposes
  cast_f2b<<<dim3(4096), 256, 0, stream>>>(X,  Xb,  BB * LL * DD / 4);
  cast_f2b<<<dim3(1024), 256, 0, stream>>>(Wv, Wvb, DD * DD / 4);
  cast_f2b<<<dim3(1024), 256, 0, stream>>>(Wd, Wdb, DD * DD / 4);
  cast_transpose_w<<<dim3(16, 16, 2), 256, 0, stream>>>(Wq, Wk, WqT, WkT);

  // 1) scores via linearity (exact fp32)
  hipMemsetAsync(xmean, 0, BB * DD * sizeof(float), stream);
  xmean_kernel<<<dim3(4, 32, 2), 256, 0, stream>>>(X, xmean);
  scores_gemm<<<dim3(16), 256, 0, stream>>>(xmean, Wq, bq, Wk, bk, scores);

  // 2) neural sort P
  bsum_kernel<<<dim3(4), 1024, 0, stream>>>(scores, bsum);
  p_kernel<<<dim3(1024, 4), 256, 0, stream>>>(scores, bsum, Pq, Pk);

  // 3) W' = P · W  (NT with B = W^T), z=4: {q,b0},{q,b1},{k,b0},{k,b1}
  GemmArgs gw = {};
  gw.gb[0] = {Pq,       WqT, nullptr, nullptr, Wp};
  gw.gb[1] = {Pq + WSZ, WqT, nullptr, nullptr, Wp + WSZ};
  gw.gb[2] = {Pk,       WkT, nullptr, nullptr, Wp + 2 * WSZ};
  gw.gb[3] = {Pk + WSZ, WkT, nullptr, nullptr, Wp + 3 * WSZ};
  gemm128<<<dim3(8, 8, 4), 256, 0, stream>>>(gw, DD, DD, DD);

  // 3b) bias' = P · bias
  pbias_kernel<<<dim3(16), 256, 0, stream>>>(Pq, Pk, bq, bk, bias4);

  // 4) qs/ks/vb in one dispatch (z=6)
  const size_t XHALF = (size_t)LL * DD;
  GemmArgs gs = {};
  gs.gb[0] = {Xb,         Wp,           bias4,        nullptr, qs};
  gs.gb[1] = {Xb + XHALF, Wp + WSZ,     bias4 + 1024, nullptr, qs + XHALF};
  gs.gb[2] = {Xb,         Wp + 2 * WSZ, bias4 + 2048, nullptr, ks};
  gs.gb[3] = {Xb + XHALF, Wp + 3 * WSZ, bias4 + 3072, nullptr, ks + XHALF};
  gs.gb[4] = {Xb,         Wvb,          bv,           nullptr, vb};
  gs.gb[5] = {Xb + XHALF, Wvb,          bv,           nullptr, vb + XHALF};
  gemm128<<<dim3(8, 16, 6), 256, 0, stream>>>(gs, LL, DD, DD);

  // 5) V transpose + euler
  transpose_v<<<dim3(32, 16, 2), 256, 0, stream>>>(vb, vbT);
  euler_kernel<<<dim3(8192, 2), 256, 0, stream>>>(qs, ks, delt, beul, lsc);

  // 6) attention (XCD-swizzled)
  attn_kernel<<<dim3(1024), 256, 0, stream>>>(qs, ks, vbT, ctx);

  // 7) output projection (hid overlays dead Wp/vb)
  GemmArgs g4 = {};
  g4.gb[0] = {ctx, Wdb, bd, hid, nullptr};
  gemm128<<<dim3(8, 32, 1), 256, 0, stream>>>(g4, BB * LL, DD, DD);

  // 8) layernorm + residual -> fp32
  ln_kernel<<<dim3(BB * LL), 256, 0, stream>>>(hid, X, gam, bet, out);
}

// Round 14
// 324.342 us; speedup vs baseline: 31.7374x; 1.2919x over previous
//
#include <hip/hip_runtime.h>

// ---------------------------------------------------------------------------
// Euler Attention forward, MI355X gfx950 — ROUND 14.
// r13: 419us = attn 83 + GEMMs ~200 (gw/g4 at 1 block/CU = no latency hiding)
// + elementwise ~40 + launches. Changes:
//  1) gemm64: 64x128 tile (12KB LDS) for gw/g4 -> 512 blocks, 2/CU.
//  2) P·bias folded into p_kernel (row already in registers).
//  3) bsum 16-block float4; scores_gemm wave-per-output (1024 blocks).
//  4) euler packed IO; Wv/Wd casts merged.
// ---------------------------------------------------------------------------

typedef unsigned short bf16_t;
typedef short frag_ab __attribute__((ext_vector_type(8)));   // 8 bf16 = 4 VGPRs
typedef float frag_cd __attribute__((ext_vector_type(4)));   // 4 fp32 acc

#define BB 2
#define LL 2048
#define DD 1024
#define HH 16
#define DH 64

__device__ __forceinline__ float b2f(bf16_t u) {
  union { unsigned int i; float f; } c; c.i = ((unsigned int)u) << 16; return c.f;
}
__device__ __forceinline__ bf16_t f2b(float f) {
  union { float f; unsigned int i; } c; c.f = f;
  unsigned int r = c.i + 0x7fffu + ((c.i >> 16) & 1u);
  return (bf16_t)(r >> 16);
}
__device__ __forceinline__ float waveMax(float v) {
#pragma unroll
  for (int m = 32; m > 0; m >>= 1) v = fmaxf(v, __shfl_xor(v, m));
  return v;
}
__device__ __forceinline__ float waveSum(float v) {
#pragma unroll
  for (int m = 32; m > 0; m >>= 1) v += __shfl_xor(v, m);
  return v;
}

// async global->LDS, 16B/lane; lds base wave-uniform (HW adds lane*16)
__device__ __forceinline__ void gll16(const bf16_t* g, bf16_t* l) {
  __builtin_amdgcn_global_load_lds(
      (const __attribute__((address_space(1))) void*)g,
      (__attribute__((address_space(3))) void*)l, 16, 0, 0);
}

// fp32 -> bf16 cast, 4 elems/thread
__global__ __launch_bounds__(256) void cast_f2b(const float* __restrict__ in,
                                                bf16_t* __restrict__ out, int n4) {
  const int i = blockIdx.x * 256 + threadIdx.x;
  if (i < n4) {
    float4 v = ((const float4*)in)[i];
    ushort4 o;
    o.x = f2b(v.x); o.y = f2b(v.y); o.z = f2b(v.z); o.w = f2b(v.w);
    ((ushort4*)out)[i] = o;
  }
}

// dual cast (z=0: Wv, z=1: Wd)
__global__ __launch_bounds__(256) void cast_wvd(const float* __restrict__ Wv,
                                                const float* __restrict__ Wd,
                                                bf16_t* __restrict__ Wvb,
                                                bf16_t* __restrict__ Wdb) {
  const float* in = blockIdx.z ? Wd : Wv;
  bf16_t* out = blockIdx.z ? Wdb : Wvb;
  const int i = blockIdx.x * 256 + threadIdx.x;
  float4 v = ((const float4*)in)[i];
  ushort4 o;
  o.x = f2b(v.x); o.y = f2b(v.y); o.z = f2b(v.z); o.w = f2b(v.w);
  ((ushort4*)out)[i] = o;
}

// cast + transpose 1024x1024 fp32 W -> bf16 W^T (z: 0=Wq, 1=Wk)
__global__ __launch_bounds__(256) void cast_transpose_w(const float* __restrict__ Wq,
                                                        const float* __restrict__ Wk,
                                                        bf16_t* __restrict__ WqT,
                                                        bf16_t* __restrict__ WkT) {
  const float* W = blockIdx.z ? Wk : Wq;
  bf16_t* WT = blockIdx.z ? WkT : WqT;
  __shared__ bf16_t T[64][72];
  const int i0 = blockIdx.x * 64, m0 = blockIdx.y * 64;
  const int tid = threadIdx.x;
#pragma unroll
  for (int it = 0; it < 4; ++it) {
    const int idx = tid + it * 256;
    const int r = idx >> 4, c4 = (idx & 15) * 4;
    float4 v = *(const float4*)&W[(size_t)(i0 + r) * DD + m0 + c4];
    T[c4 + 0][r] = f2b(v.x);
    T[c4 + 1][r] = f2b(v.y);
    T[c4 + 2][r] = f2b(v.z);
    T[c4 + 3][r] = f2b(v.w);
  }
  __syncthreads();
#pragma unroll
  for (int it = 0; it < 2; ++it) {
    const int idx = tid + it * 256;
    const int r = idx >> 3, seg = idx & 7;
    *(uint4*)&WT[(size_t)(m0 + r) * DD + i0 + seg * 8] = *(const uint4*)&T[r][seg * 8];
  }
}

// ---------------------------------------------------------------------------
struct GemmB { const bf16_t* A; const bf16_t* Bm; const float* bias; float* Cf; bf16_t* Cb; };
struct GemmArgs { GemmB gb[6]; };

// 128x128 tile MFMA GEMM (4 waves 2x2, each 64x64)
__global__ __launch_bounds__(256) void gemm128(GemmArgs ga, int M, int N, int K) {
  const GemmB g = ga.gb[blockIdx.z];
  const int bm = blockIdx.y * 128, bn = blockIdx.x * 128;
  __shared__ bf16_t As[128][32];
  __shared__ bf16_t Bs[128][32];
  bf16_t* As_f = &As[0][0];
  bf16_t* Bs_f = &Bs[0][0];
  const int tid = threadIdx.x;
  const int lane = tid & 63, w = tid >> 6;
  const int quad = lane >> 4, l16 = lane & 15;
  const int wm = (w >> 1) * 64, wn = (w & 1) * 64;
  const int wbase = w << 9;

  frag_cd acc[4][4];
#pragma unroll
  for (int i = 0; i < 4; ++i)
#pragma unroll
    for (int j = 0; j < 4; ++j)
#pragma unroll
      for (int r = 0; r < 4; ++r) acc[i][j][r] = 0.f;

  const int r0 = tid >> 2, s0 = (tid & 3) * 8;
  const int r1 = (tid + 256) >> 2, s1 = ((tid + 256) & 3) * 8;
  const size_t aoff0 = (size_t)(bm + r0) * K + s0;
  const size_t aoff1 = (size_t)(bm + r1) * K + s1;
  const size_t boff0 = (size_t)(bn + r0) * K + s0;
  const size_t boff1 = (size_t)(bn + r1) * K + s1;

  for (int k0 = 0; k0 < K; k0 += 32) {
    __syncthreads();
    gll16(g.A + aoff0 + k0, As_f + wbase);
    gll16(g.A + aoff1 + k0, As_f + 2048 + wbase);
    gll16(g.Bm + boff0 + k0, Bs_f + wbase);
    gll16(g.Bm + boff1 + k0, Bs_f + 2048 + wbase);
    __syncthreads();
    frag_ab af[4], bfr[4];
#pragma unroll
    for (int i = 0; i < 4; ++i) {
      af[i]  = *(const frag_ab*)&As[wm + i * 16 + l16][quad * 8];
      bfr[i] = *(const frag_ab*)&Bs[wn + i * 16 + l16][quad * 8];
    }
#pragma unroll
    for (int i = 0; i < 4; ++i)
#pragma unroll
      for (int j = 0; j < 4; ++j)
        acc[i][j] = __builtin_amdgcn_mfma_f32_16x16x32_bf16(af[i], bfr[j], acc[i][j], 0, 0, 0);
  }

#pragma unroll
  for (int i = 0; i < 4; ++i) {
#pragma unroll
    for (int r = 0; r < 4; ++r) {
      const int row = bm + wm + i * 16 + quad * 4 + r;
#pragma unroll
      for (int j = 0; j < 4; ++j) {
        const int col = bn + wn + j * 16 + l16;
        float v = acc[i][j][r];
        if (g.bias) v += g.bias[col];
        if (g.Cf) g.Cf[(size_t)row * N + col] = v;
        if (g.Cb) g.Cb[(size_t)row * N + col] = f2b(v);
      }
    }
  }
}

// 64x128 tile MFMA GEMM (4 waves 2x2, each 32x64) — for low-block-count GEMMs
__global__ __launch_bounds__(256) void gemm64(GemmArgs ga, int M, int N, int K) {
  const GemmB g = ga.gb[blockIdx.z];
  const int bm = blockIdx.y * 64, bn = blockIdx.x * 128;
  __shared__ bf16_t As[64][32];
  __shared__ bf16_t Bs[128][32];
  bf16_t* As_f = &As[0][0];
  bf16_t* Bs_f = &Bs[0][0];
  const int tid = threadIdx.x;
  const int lane = tid & 63, w = tid >> 6;
  const int quad = lane >> 4, l16 = lane & 15;
  const int wm = (w >> 1) * 32, wn = (w & 1) * 64;
  const int wbase = w << 9;

  frag_cd acc[2][4];
#pragma unroll
  for (int i = 0; i < 2; ++i)
#pragma unroll
    for (int j = 0; j < 4; ++j)
#pragma unroll
      for (int r = 0; r < 4; ++r) acc[i][j][r] = 0.f;

  const int r0 = tid >> 2, s0 = (tid & 3) * 8;
  const int r1 = (tid + 256) >> 2, s1 = ((tid + 256) & 3) * 8;
  const size_t aoff0 = (size_t)(bm + r0) * K + s0;               // A: 64 rows
  const size_t boff0 = (size_t)(bn + r0) * K + s0;               // B: 128 rows
  const size_t boff1 = (size_t)(bn + r1) * K + s1;

  for (int k0 = 0; k0 < K; k0 += 32) {
    __syncthreads();
    gll16(g.A + aoff0 + k0, As_f + wbase);
    gll16(g.Bm + boff0 + k0, Bs_f + wbase);
    gll16(g.Bm + boff1 + k0, Bs_f + 2048 + wbase);
    __syncthreads();
    frag_ab af[2], bfr[4];
#pragma unroll
    for (int i = 0; i < 2; ++i)
      af[i] = *(const frag_ab*)&As[wm + i * 16 + l16][quad * 8];
#pragma unroll
    for (int j = 0; j < 4; ++j)
      bfr[j] = *(const frag_ab*)&Bs[wn + j * 16 + l16][quad * 8];
#pragma unroll
    for (int i = 0; i < 2; ++i)
#pragma unroll
      for (int j = 0; j < 4; ++j)
        acc[i][j] = __builtin_amdgcn_mfma_f32_16x16x32_bf16(af[i], bfr[j], acc[i][j], 0, 0, 0);
  }

#pragma unroll
  for (int i = 0; i < 2; ++i) {
#pragma unroll
    for (int r = 0; r < 4; ++r) {
      const int row = bm + wm + i * 16 + quad * 4 + r;
#pragma unroll
      for (int j = 0; j < 4; ++j) {
        const int col = bn + wn + j * 16 + l16;
        float v = acc[i][j][r];
        if (g.bias) v += g.bias[col];
        if (g.Cf) g.Cf[(size_t)row * N + col] = v;
        if (g.Cb) g.Cb[(size_t)row * N + col] = f2b(v);
      }
    }
  }
}

// xmean[b][d] = mean over L of X[b][l][d]
__global__ __launch_bounds__(256) void xmean_kernel(const float* __restrict__ X,
                                                    float* __restrict__ xmean) {
  const int d = blockIdx.x * 256 + threadIdx.x;
  const int b = blockIdx.z;
  const int l0 = blockIdx.y * 64;
  float s = 0.f;
  for (int l = l0; l < l0 + 64; ++l)
    s += X[((size_t)b * LL + l) * DD + d];
  atomicAdd(&xmean[b * DD + d], s * (1.f / (float)LL));
}

// scores: one wave per output (grid 1024 x 4 waves = 4096 outputs)
__global__ __launch_bounds__(256) void scores_gemm(const float* __restrict__ xmean,
                                                   const float* __restrict__ Wq,
                                                   const float* __restrict__ bq,
                                                   const float* __restrict__ Wk,
                                                   const float* __restrict__ bk,
                                                   float* __restrict__ scores) {
  const int w = threadIdx.x >> 6, lane = threadIdx.x & 63;
  const int idx = blockIdx.x * 4 + w;
  const int t = idx >> 11, b = (idx >> 10) & 1, i = idx & 1023;
  const float* W = t ? Wk : Wq;
  const float* bias = t ? bk : bq;
  const float* xm = xmean + b * DD;
  float sum = 0.f;
#pragma unroll
  for (int k = 0; k < 4; ++k) {
    float4 wv = *(const float4*)&W[(size_t)i * DD + k * 256 + lane * 4];
    float4 xv = *(const float4*)&xm[k * 256 + lane * 4];
    sum += wv.x * xv.x + wv.y * xv.y + wv.z * xv.z + wv.w * xv.w;
  }
  sum = waveSum(sum);
  if (lane == 0) scores[idx] = sum + bias[i];
}

// Bsum: 16 blocks (z x 4 chunks), float4 LDS reads
__global__ __launch_bounds__(256) void bsum_kernel(const float* __restrict__ scores,
                                                   float* __restrict__ bsum) {
  __shared__ float sc[DD];
  const int z = blockIdx.x, jb = blockIdx.y, tid = threadIdx.x;
#pragma unroll
  for (int s = 0; s < 4; ++s) sc[tid + s * 256] = scores[z * DD + tid + s * 256];
  __syncthreads();
  const int j = jb * 256 + tid;
  const float si = sc[j];
  float s = 0.f;
  for (int m = 0; m < DD; m += 4) {
    float4 v = *(const float4*)&sc[m];
    s += fabsf(si - v.x) + fabsf(si - v.y) + fabsf(si - v.z) + fabsf(si - v.w);
  }
  bsum[z * DD + j] = s;
}

// P row + folded bias' = (sum_j p_j * bias_j)
__global__ __launch_bounds__(256) void p_kernel(const float* __restrict__ scores,
                                                const float* __restrict__ bsum,
                                                const float* __restrict__ bq,
                                                const float* __restrict__ bk,
                                                bf16_t* __restrict__ Pq,
                                                bf16_t* __restrict__ Pk,
                                                float* __restrict__ bias4) {
  const int i = blockIdx.x;
  const int z = blockIdx.y;
  const int t = z >> 1, b = z & 1;
  const float* sc = scores + z * DD;
  const float* bs = bsum + z * DD;
  const float* bias = t ? bk : bq;
  const float scal = 1023.f - 2.f * (float)i;
  const int tid = threadIdx.x;
  __shared__ float redA[4], redB[4], redC[4];

  float lg[4], bb[4];
  float mx = -1e30f;
#pragma unroll
  for (int s = 0; s < 4; ++s) {
    const int j = tid + s * 256;
    lg[s] = sc[j] * scal - bs[j];
    bb[s] = bias[j];
    mx = fmaxf(mx, lg[s]);
  }
  mx = waveMax(mx);
  if ((tid & 63) == 0) redA[tid >> 6] = mx;
  __syncthreads();
  const float M = fmaxf(fmaxf(redA[0], redA[1]), fmaxf(redA[2], redA[3]));
  float sum = 0.f, dot = 0.f;
#pragma unroll
  for (int s = 0; s < 4; ++s) {
    lg[s] = __expf(lg[s] - M);
    sum += lg[s];
    dot += lg[s] * bb[s];
  }
  sum = waveSum(sum); dot = waveSum(dot);
  if ((tid & 63) == 0) { redB[tid >> 6] = sum; redC[tid >> 6] = dot; }
  __syncthreads();
  const float inv = 1.f / (redB[0] + redB[1] + redB[2] + redB[3]);
  bf16_t* P = (t ? Pk : Pq) + ((size_t)b << 20) + (size_t)i * DD;
#pragma unroll
  for (int s = 0; s < 4; ++s) P[tid + s * 256] = f2b(lg[s] * inv);
  if (tid == 0)
    bias4[t * 2048 + b * 1024 + i] = (redC[0] + redC[1] + redC[2] + redC[3]) * inv;
}

// euler transform: packed uint IO, q and k in one launch
__global__ __launch_bounds__(256) void euler_kernel(bf16_t* __restrict__ qs,
                                                    bf16_t* __restrict__ ks,
                                                    const float* __restrict__ delta,
                                                    const float* __restrict__ beul,
                                                    const float* __restrict__ lsc) {
  const int isq = (blockIdx.y == 0);
  unsigned int* buf = (unsigned int*)(isq ? qs : ks);
  const int idx = blockIdx.x * 256 + threadIdx.x;
  const int c = idx & 511;
  const size_t n = idx >> 9;
  const unsigned int u = buf[n * 512 + c];
  const float r = b2f((bf16_t)(u & 0xffffu));
  const float p = b2f((bf16_t)(u >> 16));
  float lam = sqrtf(r * r + p * p + 1e-6f);
  float th = atan2f(p, r) * delta[c];
  if (isq) th += beul[c];
  lam *= __expf(fminf(fmaxf(lsc[c], -5.f), 5.f));
  float sn, cs;
  __sincosf(th, &sn, &cs);
  buf[n * 512 + c] = ((unsigned int)f2b(lam * sn) << 16) | (unsigned int)f2b(lam * cs);
}

// V transpose: vb[(b*L + l)][d] -> vbT[(b*DD + d)][l]
__global__ __launch_bounds__(256) void transpose_v(const bf16_t* __restrict__ vb,
                                                   bf16_t* __restrict__ vbT) {
  __shared__ bf16_t T[64][72];
  const int l0 = blockIdx.x * 64, d0 = blockIdx.y * 64, b = blockIdx.z;
  const int tid = threadIdx.x;
  for (int i = tid; i < 512; i += 256) {
    const int r = i >> 3, seg = i & 7;
    uint4 v = *(const uint4*)&vb[((size_t)b * LL + l0 + r) * DD + d0 + seg * 8];
    const bf16_t* vs = (const bf16_t*)&v;
#pragma unroll
    for (int j = 0; j < 8; ++j) T[seg * 8 + j][r] = vs[j];
  }
  __syncthreads();
  for (int i = tid; i < 512; i += 256) {
    const int r = i >> 3, seg = i & 7;
    *(uint4*)&vbT[((size_t)b * DD + d0 + r) * LL + l0 + seg * 8] =
        *(const uint4*)&T[r][seg * 8];
  }
}

// ---------------------------------------------------------------------------
// Flash attention: padded LDS, V^T staged, fixed-offset exp, XCD swizzle.
// ---------------------------------------------------------------------------
__global__ __launch_bounds__(256) void attn_kernel(const bf16_t* __restrict__ Q,
                                                   const bf16_t* __restrict__ Kt,
                                                   const bf16_t* __restrict__ VT,
                                                   bf16_t* __restrict__ O) {
  const int bid = blockIdx.x;
  const int g = (bid & 7) + 8 * (bid >> 8);
  const int qt = (bid >> 3) & 31;
  const int b = g >> 4, h = g & 15;
  const int q0 = qt * 64;
  const int tid = threadIdx.x, w = tid >> 6, lane = tid & 63;
  const int quad = lane >> 4, l16 = lane & 15;
  __shared__ bf16_t Ks[64][72], Vs[64][72], Ps[64][72];
  const size_t base = ((size_t)b * LL) * DD + (size_t)h * DH;
  const size_t vtb = (size_t)(b * DD + h * DH) * LL;

  for (int i = tid; i < 512; i += 256) {
    const int r = i >> 3, seg = i & 7;
    *(uint4*)&Ps[r][seg * 8] = *(const uint4*)&Q[base + (size_t)(q0 + r) * DD + seg * 8];
  }
  __syncthreads();
  frag_ab aq0 = *(const frag_ab*)&Ps[w * 16 + l16][quad * 8];
  frag_ab aq1 = *(const frag_ab*)&Ps[w * 16 + l16][32 + quad * 8];

  float l_[4] = {0.f, 0.f, 0.f, 0.f};
  frag_cd o_[4];
#pragma unroll
  for (int n = 0; n < 4; ++n)
#pragma unroll
    for (int r = 0; r < 4; ++r) o_[n][r] = 0.f;

  for (int kt = 0; kt < LL / 64; ++kt) {
    __syncthreads();
    for (int i = tid; i < 512; i += 256) {
      const int r = i >> 3, seg = i & 7;
      *(uint4*)&Ks[r][seg * 8] = *(const uint4*)&Kt[base + (size_t)(kt * 64 + r) * DD + seg * 8];
      *(uint4*)&Vs[r][seg * 8] = *(const uint4*)&VT[vtb + (size_t)r * LL + kt * 64 + seg * 8];
    }
    __syncthreads();

    frag_cd s_[4];
#pragma unroll
    for (int n = 0; n < 4; ++n) {
      frag_ab b0 = *(const frag_ab*)&Ks[n * 16 + l16][quad * 8];
      frag_ab b1 = *(const frag_ab*)&Ks[n * 16 + l16][32 + quad * 8];
      frag_cd z; z[0] = z[1] = z[2] = z[3] = 0.f;
      z = __builtin_amdgcn_mfma_f32_16x16x32_bf16(aq0, b0, z, 0, 0, 0);
      s_[n] = __builtin_amdgcn_mfma_f32_16x16x32_bf16(aq1, b1, z, 0, 0, 0);
    }

#pragma unroll
    for (int n = 0; n < 4; ++n)
#pragma unroll
      for (int r = 0; r < 4; ++r) {
        const float p = __expf(s_[n][r] * 0.125f - 12.f);
        l_[r] += p;
        Ps[w * 16 + quad * 4 + r][n * 16 + l16] = f2b(p);
      }

    frag_ab ap0 = *(const frag_ab*)&Ps[w * 16 + l16][quad * 8];
    frag_ab ap1 = *(const frag_ab*)&Ps[w * 16 + l16][32 + quad * 8];
#pragma unroll
    for (int n = 0; n < 4; ++n) {
      frag_ab bv0 = *(const frag_ab*)&Vs[n * 16 + l16][quad * 8];
      frag_ab bv1 = *(const frag_ab*)&Vs[n * 16 + l16][32 + quad * 8];
      o_[n] = __builtin_amdgcn_mfma_f32_16x16x32_bf16(ap0, bv0, o_[n], 0, 0, 0);
      o_[n] = __builtin_amdgcn_mfma_f32_16x16x32_bf16(ap1, bv1, o_[n], 0, 0, 0);
    }
  }

#pragma unroll
  for (int r = 0; r < 4; ++r) {
#pragma unroll
    for (int m = 8; m > 0; m >>= 1) l_[r] += __shfl_xor(l_[r], m);
  }
#pragma unroll
  for (int n = 0; n < 4; ++n)
#pragma unroll
    for (int r = 0; r < 4; ++r) {
      const float v = o_[n][r] / l_[r];
      O[base + (size_t)(q0 + w * 16 + quad * 4 + r) * DD + n * 16 + l16] = f2b(v);
    }
}

// layernorm(hidden + X) * gamma + beta -> FP32 out
__global__ __launch_bounds__(256) void ln_kernel(const float* __restrict__ hidden,
                                                 const float* __restrict__ x0,
                                                 const float* __restrict__ gamma,
                                                 const float* __restrict__ beta,
                                                 float* __restrict__ out) {
  const int row = blockIdx.x;
  const int tid = threadIdx.x;
  __shared__ float red1[4], red2[4];
  float v[4];
  float s1 = 0.f, s2 = 0.f;
#pragma unroll
  for (int s = 0; s < 4; ++s) {
    const int c = tid + s * 256;
    const float x = hidden[(size_t)row * DD + c] + x0[(size_t)row * DD + c];
    v[s] = x; s1 += x; s2 += x * x;
  }
  s1 = waveSum(s1); s2 = waveSum(s2);
  if ((tid & 63) == 0) { red1[tid >> 6] = s1; red2[tid >> 6] = s2; }
  __syncthreads();
  const float t1 = red1[0] + red1[1] + red1[2] + red1[3];
  const float t2 = red2[0] + red2[1] + red2[2] + red2[3];
  const float mu = t1 * (1.f / DD);
  const float var = t2 * (1.f / DD) - mu * mu;
  const float inv = rsqrtf(var + 1e-12f);
#pragma unroll
  for (int s = 0; s < 4; ++s) {
    const int c = tid + s * 256;
    out[(size_t)row * DD + c] = (v[s] - mu) * inv * gamma[c] + beta[c];
  }
}

// ---------------------------------------------------------------------------
extern "C" void kernel_launch(void* const* d_in, const int* in_sizes, int n_in,
                              void* d_out, int out_size, void* d_ws, size_t ws_size,
                              hipStream_t stream) {
  const float* X    = (const float*)d_in[0];
  const float* Wq   = (const float*)d_in[1];
  const float* bq   = (const float*)d_in[2];
  const float* Wk   = (const float*)d_in[3];
  const float* bk   = (const float*)d_in[4];
  const float* Wv   = (const float*)d_in[5];
  const float* bv   = (const float*)d_in[6];
  const float* Wd   = (const float*)d_in[7];
  const float* bd   = (const float*)d_in[8];
  const float* gam  = (const float*)d_in[9];
  const float* bet  = (const float*)d_in[10];
  const float* delt = (const float*)d_in[11];
  const float* beul = (const float*)d_in[12];
  const float* lsc  = (const float*)d_in[13];
  float* out = (float*)d_out;

  char* w = (char*)d_ws;
  const size_t MB = 1024ull * 1024ull;
  bf16_t* Xb  = (bf16_t*)(w + 0 * MB);    // 8MB
  bf16_t* Wvb = (bf16_t*)(w + 8 * MB);    // 2MB
  bf16_t* Wdb = (bf16_t*)(w + 10 * MB);   // 2MB
  bf16_t* WqT = (bf16_t*)(w + 12 * MB);   // 2MB
  bf16_t* WkT = (bf16_t*)(w + 14 * MB);   // 2MB
  bf16_t* Pq  = (bf16_t*)(w + 16 * MB);   // 4MB
  bf16_t* Pk  = (bf16_t*)(w + 20 * MB);   // 4MB
  bf16_t* Wp  = (bf16_t*)(w + 24 * MB);   // 8MB: W'q[2], W'k[2]
  bf16_t* vb  = (bf16_t*)(w + 32 * MB);   // 8MB  (dead after transpose_v)
  bf16_t* qs  = (bf16_t*)(w + 40 * MB);   // 8MB
  bf16_t* ks  = (bf16_t*)(w + 48 * MB);   // 8MB
  bf16_t* vbT = (bf16_t*)(w + 56 * MB);   // 8MB
  bf16_t* ctx = (bf16_t*)(w + 64 * MB);   // 8MB
  float*  hid = (float*)(w + 24 * MB);    // 16MB overlays Wp+vb (dead after attn)
  float*  xmean  = (float*)(w + 72 * MB);             // 8KB
  float*  scores = (float*)(w + 72 * MB + 16384);     // 16KB
  float*  bsum   = (float*)(w + 72 * MB + 32768);     // 16KB
  float*  bias4  = (float*)(w + 72 * MB + 49152);     // 16KB [t][b][j]

  const size_t WSZ = (size_t)DD * DD;

  // 0) casts + W transposes
  cast_f2b<<<dim3(4096), 256, 0, stream>>>(X, Xb, BB * LL * DD / 4);
  cast_wvd<<<dim3(1024, 1, 2), 256, 0, stream>>>(Wv, Wd, Wvb, Wdb);
  cast_transpose_w<<<dim3(16, 16, 2), 256, 0, stream>>>(Wq, Wk, WqT, WkT);

  // 1) scores via linearity (exact fp32)
  hipMemsetAsync(xmean, 0, BB * DD * sizeof(float), stream);
  xmean_kernel<<<dim3(4, 32, 2), 256, 0, stream>>>(X, xmean);
  scores_gemm<<<dim3(1024), 256, 0, stream>>>(xmean, Wq, bq, Wk, bk, scores);

  // 2) neural sort P (+ folded bias')
  bsum_kernel<<<dim3(4, 4), 256, 0, stream>>>(scores, bsum);
  p_kernel<<<dim3(1024, 4), 256, 0, stream>>>(scores, bsum, bq, bk, Pq, Pk, bias4);

  // 3) W' = P · W  (gemm64: 512 blocks, 2/CU)
  GemmArgs gw = {};
  gw.gb[0] = {Pq,       WqT, nullptr, nullptr, Wp};
  gw.gb[1] = {Pq + WSZ, WqT, nullptr, nullptr, Wp + WSZ};
  gw.gb[2] = {Pk,       WkT, nullptr, nullptr, Wp + 2 * WSZ};
  gw.gb[3] = {Pk + WSZ, WkT, nullptr, nullptr, Wp + 3 * WSZ};
  gemm64<<<dim3(8, 16, 4), 256, 0, stream>>>(gw, DD, DD, DD);

  // 4) qs/ks/vb (gemm128, 768 blocks, 3/CU)
  const size_t XHALF = (size_t)LL * DD;
  GemmArgs gs = {};
  gs.gb[0] = {Xb,         Wp,           bias4,        nullptr, qs};
  gs.gb[1] = {Xb + XHALF, Wp + WSZ,     bias4 + 1024, nullptr, qs + XHALF};
  gs.gb[2] = {Xb,         Wp + 2 * WSZ, bias4 + 2048, nullptr, ks};
  gs.gb[3] = {Xb + XHALF, Wp + 3 * WSZ, bias4 + 3072, nullptr, ks + XHALF};
  gs.gb[4] = {Xb,         Wvb,          bv,           nullptr, vb};
  gs.gb[5] = {Xb + XHALF, Wvb,          bv,           nullptr, vb + XHALF};
  gemm128<<<dim3(8, 16, 6), 256, 0, stream>>>(gs, LL, DD, DD);

  // 5) V transpose + euler
  transpose_v<<<dim3(32, 16, 2), 256, 0, stream>>>(vb, vbT);
  euler_kernel<<<dim3(8192, 2), 256, 0, stream>>>(qs, ks, delt, beul, lsc);

  // 6) attention (XCD-swizzled)
  attn_kernel<<<dim3(1024), 256, 0, stream>>>(qs, ks, vbT, ctx);

  // 7) output projection (gemm64: 512 blocks)
  GemmArgs g4 = {};
  g4.gb[0] = {ctx, Wdb, bd, hid, nullptr};
  gemm64<<<dim3(8, 64, 1), 256, 0, stream>>>(g4, BB * LL, DD, DD);

  // 8) layernorm + residual -> fp32
  ln_kernel<<<dim3(BB * LL), 256, 0, stream>>>(hid, X, gam, bet, out);
}

// Round 15
// 320.341 us; speedup vs baseline: 32.1338x; 1.0125x over previous
//
#include <hip/hip_runtime.h>

// ---------------------------------------------------------------------------
// Euler Attention forward, MI355X gfx950 — ROUND 15.
// r14: 324us, attn 83us (VALU 44%, 9.5M LDS-conflict cycles from 16 scalar
// ds_write_b16 of P per k-tile). Change: compute S^T (A=K, B=Q) so P^T's
// C-layout gives 4 consecutive keys per lane -> v_perm pack + 4x ds_write_b64
// (2-way banks = free). PV stage unchanged. g4 -> bf16 hid (halved traffic).
// ---------------------------------------------------------------------------

typedef unsigned short bf16_t;
typedef short frag_ab __attribute__((ext_vector_type(8)));   // 8 bf16 = 4 VGPRs
typedef float frag_cd __attribute__((ext_vector_type(4)));   // 4 fp32 acc

#define BB 2
#define LL 2048
#define DD 1024
#define HH 16
#define DH 64

__device__ __forceinline__ float b2f(bf16_t u) {
  union { unsigned int i; float f; } c; c.i = ((unsigned int)u) << 16; return c.f;
}
__device__ __forceinline__ bf16_t f2b(float f) {
  union { float f; unsigned int i; } c; c.f = f;
  unsigned int r = c.i + 0x7fffu + ((c.i >> 16) & 1u);
  return (bf16_t)(r >> 16);
}
__device__ __forceinline__ unsigned int fbits(float f) {
  union { float f; unsigned int i; } c; c.f = f; return c.i;
}
__device__ __forceinline__ float waveMax(float v) {
#pragma unroll
  for (int m = 32; m > 0; m >>= 1) v = fmaxf(v, __shfl_xor(v, m));
  return v;
}
__device__ __forceinline__ float waveSum(float v) {
#pragma unroll
  for (int m = 32; m > 0; m >>= 1) v += __shfl_xor(v, m);
  return v;
}

// async global->LDS, 16B/lane; lds base wave-uniform (HW adds lane*16)
__device__ __forceinline__ void gll16(const bf16_t* g, bf16_t* l) {
  __builtin_amdgcn_global_load_lds(
      (const __attribute__((address_space(1))) void*)g,
      (__attribute__((address_space(3))) void*)l, 16, 0, 0);
}

// fp32 -> bf16 cast, 4 elems/thread
__global__ __launch_bounds__(256) void cast_f2b(const float* __restrict__ in,
                                                bf16_t* __restrict__ out, int n4) {
  const int i = blockIdx.x * 256 + threadIdx.x;
  if (i < n4) {
    float4 v = ((const float4*)in)[i];
    ushort4 o;
    o.x = f2b(v.x); o.y = f2b(v.y); o.z = f2b(v.z); o.w = f2b(v.w);
    ((ushort4*)out)[i] = o;
  }
}

// dual cast (z=0: Wv, z=1: Wd)
__global__ __launch_bounds__(256) void cast_wvd(const float* __restrict__ Wv,
                                                const float* __restrict__ Wd,
                                                bf16_t* __restrict__ Wvb,
                                                bf16_t* __restrict__ Wdb) {
  const float* in = blockIdx.z ? Wd : Wv;
  bf16_t* out = blockIdx.z ? Wdb : Wvb;
  const int i = blockIdx.x * 256 + threadIdx.x;
  float4 v = ((const float4*)in)[i];
  ushort4 o;
  o.x = f2b(v.x); o.y = f2b(v.y); o.z = f2b(v.z); o.w = f2b(v.w);
  ((ushort4*)out)[i] = o;
}

// cast + transpose 1024x1024 fp32 W -> bf16 W^T (z: 0=Wq, 1=Wk)
__global__ __launch_bounds__(256) void cast_transpose_w(const float* __restrict__ Wq,
                                                        const float* __restrict__ Wk,
                                                        bf16_t* __restrict__ WqT,
                                                        bf16_t* __restrict__ WkT) {
  const float* W = blockIdx.z ? Wk : Wq;
  bf16_t* WT = blockIdx.z ? WkT : WqT;
  __shared__ bf16_t T[64][72];
  const int i0 = blockIdx.x * 64, m0 = blockIdx.y * 64;
  const int tid = threadIdx.x;
#pragma unroll
  for (int it = 0; it < 4; ++it) {
    const int idx = tid + it * 256;
    const int r = idx >> 4, c4 = (idx & 15) * 4;
    float4 v = *(const float4*)&W[(size_t)(i0 + r) * DD + m0 + c4];
    T[c4 + 0][r] = f2b(v.x);
    T[c4 + 1][r] = f2b(v.y);
    T[c4 + 2][r] = f2b(v.z);
    T[c4 + 3][r] = f2b(v.w);
  }
  __syncthreads();
#pragma unroll
  for (int it = 0; it < 2; ++it) {
    const int idx = tid + it * 256;
    const int r = idx >> 3, seg = idx & 7;
    *(uint4*)&WT[(size_t)(m0 + r) * DD + i0 + seg * 8] = *(const uint4*)&T[r][seg * 8];
  }
}

// ---------------------------------------------------------------------------
struct GemmB { const bf16_t* A; const bf16_t* Bm; const float* bias; float* Cf; bf16_t* Cb; };
struct GemmArgs { GemmB gb[6]; };

// 128x128 tile MFMA GEMM (4 waves 2x2, each 64x64)
__global__ __launch_bounds__(256) void gemm128(GemmArgs ga, int M, int N, int K) {
  const GemmB g = ga.gb[blockIdx.z];
  const int bm = blockIdx.y * 128, bn = blockIdx.x * 128;
  __shared__ bf16_t As[128][32];
  __shared__ bf16_t Bs[128][32];
  bf16_t* As_f = &As[0][0];
  bf16_t* Bs_f = &Bs[0][0];
  const int tid = threadIdx.x;
  const int lane = tid & 63, w = tid >> 6;
  const int quad = lane >> 4, l16 = lane & 15;
  const int wm = (w >> 1) * 64, wn = (w & 1) * 64;
  const int wbase = w << 9;

  frag_cd acc[4][4];
#pragma unroll
  for (int i = 0; i < 4; ++i)
#pragma unroll
    for (int j = 0; j < 4; ++j)
#pragma unroll
      for (int r = 0; r < 4; ++r) acc[i][j][r] = 0.f;

  const int r0 = tid >> 2, s0 = (tid & 3) * 8;
  const int r1 = (tid + 256) >> 2, s1 = ((tid + 256) & 3) * 8;
  const size_t aoff0 = (size_t)(bm + r0) * K + s0;
  const size_t aoff1 = (size_t)(bm + r1) * K + s1;
  const size_t boff0 = (size_t)(bn + r0) * K + s0;
  const size_t boff1 = (size_t)(bn + r1) * K + s1;

  for (int k0 = 0; k0 < K; k0 += 32) {
    __syncthreads();
    gll16(g.A + aoff0 + k0, As_f + wbase);
    gll16(g.A + aoff1 + k0, As_f + 2048 + wbase);
    gll16(g.Bm + boff0 + k0, Bs_f + wbase);
    gll16(g.Bm + boff1 + k0, Bs_f + 2048 + wbase);
    __syncthreads();
    frag_ab af[4], bfr[4];
#pragma unroll
    for (int i = 0; i < 4; ++i) {
      af[i]  = *(const frag_ab*)&As[wm + i * 16 + l16][quad * 8];
      bfr[i] = *(const frag_ab*)&Bs[wn + i * 16 + l16][quad * 8];
    }
#pragma unroll
    for (int i = 0; i < 4; ++i)
#pragma unroll
      for (int j = 0; j < 4; ++j)
        acc[i][j] = __builtin_amdgcn_mfma_f32_16x16x32_bf16(af[i], bfr[j], acc[i][j], 0, 0, 0);
  }

#pragma unroll
  for (int i = 0; i < 4; ++i) {
#pragma unroll
    for (int r = 0; r < 4; ++r) {
      const int row = bm + wm + i * 16 + quad * 4 + r;
#pragma unroll
      for (int j = 0; j < 4; ++j) {
        const int col = bn + wn + j * 16 + l16;
        float v = acc[i][j][r];
        if (g.bias) v += g.bias[col];
        if (g.Cf) g.Cf[(size_t)row * N + col] = v;
        if (g.Cb) g.Cb[(size_t)row * N + col] = f2b(v);
      }
    }
  }
}

// 64x128 tile MFMA GEMM (4 waves 2x2, each 32x64) — for low-block-count GEMMs
__global__ __launch_bounds__(256) void gemm64(GemmArgs ga, int M, int N, int K) {
  const GemmB g = ga.gb[blockIdx.z];
  const int bm = blockIdx.y * 64, bn = blockIdx.x * 128;
  __shared__ bf16_t As[64][32];
  __shared__ bf16_t Bs[128][32];
  bf16_t* As_f = &As[0][0];
  bf16_t* Bs_f = &Bs[0][0];
  const int tid = threadIdx.x;
  const int lane = tid & 63, w = tid >> 6;
  const int quad = lane >> 4, l16 = lane & 15;
  const int wm = (w >> 1) * 32, wn = (w & 1) * 64;
  const int wbase = w << 9;

  frag_cd acc[2][4];
#pragma unroll
  for (int i = 0; i < 2; ++i)
#pragma unroll
    for (int j = 0; j < 4; ++j)
#pragma unroll
      for (int r = 0; r < 4; ++r) acc[i][j][r] = 0.f;

  const int r0 = tid >> 2, s0 = (tid & 3) * 8;
  const int r1 = (tid + 256) >> 2, s1 = ((tid + 256) & 3) * 8;
  const size_t aoff0 = (size_t)(bm + r0) * K + s0;
  const size_t boff0 = (size_t)(bn + r0) * K + s0;
  const size_t boff1 = (size_t)(bn + r1) * K + s1;

  for (int k0 = 0; k0 < K; k0 += 32) {
    __syncthreads();
    gll16(g.A + aoff0 + k0, As_f + wbase);
    gll16(g.Bm + boff0 + k0, Bs_f + wbase);
    gll16(g.Bm + boff1 + k0, Bs_f + 2048 + wbase);
    __syncthreads();
    frag_ab af[2], bfr[4];
#pragma unroll
    for (int i = 0; i < 2; ++i)
      af[i] = *(const frag_ab*)&As[wm + i * 16 + l16][quad * 8];
#pragma unroll
    for (int j = 0; j < 4; ++j)
      bfr[j] = *(const frag_ab*)&Bs[wn + j * 16 + l16][quad * 8];
#pragma unroll
    for (int i = 0; i < 2; ++i)
#pragma unroll
      for (int j = 0; j < 4; ++j)
        acc[i][j] = __builtin_amdgcn_mfma_f32_16x16x32_bf16(af[i], bfr[j], acc[i][j], 0, 0, 0);
  }

#pragma unroll
  for (int i = 0; i < 2; ++i) {
#pragma unroll
    for (int r = 0; r < 4; ++r) {
      const int row = bm + wm + i * 16 + quad * 4 + r;
#pragma unroll
      for (int j = 0; j < 4; ++j) {
        const int col = bn + wn + j * 16 + l16;
        float v = acc[i][j][r];
        if (g.bias) v += g.bias[col];
        if (g.Cf) g.Cf[(size_t)row * N + col] = v;
        if (g.Cb) g.Cb[(size_t)row * N + col] = f2b(v);
      }
    }
  }
}

// xmean[b][d] = mean over L of X[b][l][d]
__global__ __launch_bounds__(256) void xmean_kernel(const float* __restrict__ X,
                                                    float* __restrict__ xmean) {
  const int d = blockIdx.x * 256 + threadIdx.x;
  const int b = blockIdx.z;
  const int l0 = blockIdx.y * 64;
  float s = 0.f;
  for (int l = l0; l < l0 + 64; ++l)
    s += X[((size_t)b * LL + l) * DD + d];
  atomicAdd(&xmean[b * DD + d], s * (1.f / (float)LL));
}

// scores: one wave per output
__global__ __launch_bounds__(256) void scores_gemm(const float* __restrict__ xmean,
                                                   const float* __restrict__ Wq,
                                                   const float* __restrict__ bq,
                                                   const float* __restrict__ Wk,
                                                   const float* __restrict__ bk,
                                                   float* __restrict__ scores) {
  const int w = threadIdx.x >> 6, lane = threadIdx.x & 63;
  const int idx = blockIdx.x * 4 + w;
  const int t = idx >> 11, b = (idx >> 10) & 1, i = idx & 1023;
  const float* W = t ? Wk : Wq;
  const float* bias = t ? bk : bq;
  const float* xm = xmean + b * DD;
  float sum = 0.f;
#pragma unroll
  for (int k = 0; k < 4; ++k) {
    float4 wv = *(const float4*)&W[(size_t)i * DD + k * 256 + lane * 4];
    float4 xv = *(const float4*)&xm[k * 256 + lane * 4];
    sum += wv.x * xv.x + wv.y * xv.y + wv.z * xv.z + wv.w * xv.w;
  }
  sum = waveSum(sum);
  if (lane == 0) scores[idx] = sum + bias[i];
}

// Bsum: 16 blocks, float4 LDS reads
__global__ __launch_bounds__(256) void bsum_kernel(const float* __restrict__ scores,
                                                   float* __restrict__ bsum) {
  __shared__ float sc[DD];
  const int z = blockIdx.x, jb = blockIdx.y, tid = threadIdx.x;
#pragma unroll
  for (int s = 0; s < 4; ++s) sc[tid + s * 256] = scores[z * DD + tid + s * 256];
  __syncthreads();
  const int j = jb * 256 + tid;
  const float si = sc[j];
  float s = 0.f;
  for (int m = 0; m < DD; m += 4) {
    float4 v = *(const float4*)&sc[m];
    s += fabsf(si - v.x) + fabsf(si - v.y) + fabsf(si - v.z) + fabsf(si - v.w);
  }
  bsum[z * DD + j] = s;
}

// P row + folded bias'
__global__ __launch_bounds__(256) void p_kernel(const float* __restrict__ scores,
                                                const float* __restrict__ bsum,
                                                const float* __restrict__ bq,
                                                const float* __restrict__ bk,
                                                bf16_t* __restrict__ Pq,
                                                bf16_t* __restrict__ Pk,
                                                float* __restrict__ bias4) {
  const int i = blockIdx.x;
  const int z = blockIdx.y;
  const int t = z >> 1, b = z & 1;
  const float* sc = scores + z * DD;
  const float* bs = bsum + z * DD;
  const float* bias = t ? bk : bq;
  const float scal = 1023.f - 2.f * (float)i;
  const int tid = threadIdx.x;
  __shared__ float redA[4], redB[4], redC[4];

  float lg[4], bb[4];
  float mx = -1e30f;
#pragma unroll
  for (int s = 0; s < 4; ++s) {
    const int j = tid + s * 256;
    lg[s] = sc[j] * scal - bs[j];
    bb[s] = bias[j];
    mx = fmaxf(mx, lg[s]);
  }
  mx = waveMax(mx);
  if ((tid & 63) == 0) redA[tid >> 6] = mx;
  __syncthreads();
  const float M = fmaxf(fmaxf(redA[0], redA[1]), fmaxf(redA[2], redA[3]));
  float sum = 0.f, dot = 0.f;
#pragma unroll
  for (int s = 0; s < 4; ++s) {
    lg[s] = __expf(lg[s] - M);
    sum += lg[s];
    dot += lg[s] * bb[s];
  }
  sum = waveSum(sum); dot = waveSum(dot);
  if ((tid & 63) == 0) { redB[tid >> 6] = sum; redC[tid >> 6] = dot; }
  __syncthreads();
  const float inv = 1.f / (redB[0] + redB[1] + redB[2] + redB[3]);
  bf16_t* P = (t ? Pk : Pq) + ((size_t)b << 20) + (size_t)i * DD;
#pragma unroll
  for (int s = 0; s < 4; ++s) P[tid + s * 256] = f2b(lg[s] * inv);
  if (tid == 0)
    bias4[t * 2048 + b * 1024 + i] = (redC[0] + redC[1] + redC[2] + redC[3]) * inv;
}

// euler transform: packed uint IO, q and k in one launch
__global__ __launch_bounds__(256) void euler_kernel(bf16_t* __restrict__ qs,
                                                    bf16_t* __restrict__ ks,
                                                    const float* __restrict__ delta,
                                                    const float* __restrict__ beul,
                                                    const float* __restrict__ lsc) {
  const int isq = (blockIdx.y == 0);
  unsigned int* buf = (unsigned int*)(isq ? qs : ks);
  const int idx = blockIdx.x * 256 + threadIdx.x;
  const int c = idx & 511;
  const size_t n = idx >> 9;
  const unsigned int u = buf[n * 512 + c];
  const float r = b2f((bf16_t)(u & 0xffffu));
  const float p = b2f((bf16_t)(u >> 16));
  float lam = sqrtf(r * r + p * p + 1e-6f);
  float th = atan2f(p, r) * delta[c];
  if (isq) th += beul[c];
  lam *= __expf(fminf(fmaxf(lsc[c], -5.f), 5.f));
  float sn, cs;
  __sincosf(th, &sn, &cs);
  buf[n * 512 + c] = ((unsigned int)f2b(lam * sn) << 16) | (unsigned int)f2b(lam * cs);
}

// V transpose: vb[(b*L + l)][d] -> vbT[(b*DD + d)][l]
__global__ __launch_bounds__(256) void transpose_v(const bf16_t* __restrict__ vb,
                                                   bf16_t* __restrict__ vbT) {
  __shared__ bf16_t T[64][72];
  const int l0 = blockIdx.x * 64, d0 = blockIdx.y * 64, b = blockIdx.z;
  const int tid = threadIdx.x;
  for (int i = tid; i < 512; i += 256) {
    const int r = i >> 3, seg = i & 7;
    uint4 v = *(const uint4*)&vb[((size_t)b * LL + l0 + r) * DD + d0 + seg * 8];
    const bf16_t* vs = (const bf16_t*)&v;
#pragma unroll
    for (int j = 0; j < 8; ++j) T[seg * 8 + j][r] = vs[j];
  }
  __syncthreads();
  for (int i = tid; i < 512; i += 256) {
    const int r = i >> 3, seg = i & 7;
    *(uint4*)&vbT[((size_t)b * DD + d0 + r) * LL + l0 + seg * 8] =
        *(const uint4*)&T[r][seg * 8];
  }
}

// ---------------------------------------------------------------------------
// Flash attention v3: S^T form. QK^T computed as S^T = K·Q^T (A=K, B=Q) so
// lane regs hold 4 consecutive keys of one P row -> v_perm pack + ds_write_b64
// (2-way banks, free). PV stage identical to v2. Fixed-offset exp.
// ---------------------------------------------------------------------------
__global__ __launch_bounds__(256) void attn_kernel(const bf16_t* __restrict__ Q,
                                                   const bf16_t* __restrict__ Kt,
                                                   const bf16_t* __restrict__ VT,
                                                   bf16_t* __restrict__ O) {
  const int bid = blockIdx.x;
  const int g = (bid & 7) + 8 * (bid >> 8);
  const int qt = (bid >> 3) & 31;
  const int b = g >> 4, h = g & 15;
  const int q0 = qt * 64;
  const int tid = threadIdx.x, w = tid >> 6, lane = tid & 63;
  const int quad = lane >> 4, l16 = lane & 15;
  __shared__ bf16_t Ks[64][72], Vs[64][72], Ps[64][72], Qs[64][72];
  const size_t base = ((size_t)b * LL) * DD + (size_t)h * DH;
  const size_t vtb = (size_t)(b * DD + h * DH) * LL;

  for (int i = tid; i < 512; i += 256) {
    const int r = i >> 3, seg = i & 7;
    *(uint4*)&Qs[r][seg * 8] = *(const uint4*)&Q[base + (size_t)(q0 + r) * DD + seg * 8];
  }
  __syncthreads();
  // Q as B-operand: B[n=query l16][k=d]
  frag_ab bq0 = *(const frag_ab*)&Qs[w * 16 + l16][quad * 8];
  frag_ab bq1 = *(const frag_ab*)&Qs[w * 16 + l16][32 + quad * 8];

  float lsum = 0.f;                      // partial row-sum for query w*16+l16
  frag_cd o_[4];
#pragma unroll
  for (int n = 0; n < 4; ++n)
#pragma unroll
    for (int r = 0; r < 4; ++r) o_[n][r] = 0.f;

  for (int kt = 0; kt < LL / 64; ++kt) {
    __syncthreads();
    for (int i = tid; i < 512; i += 256) {
      const int r = i >> 3, seg = i & 7;
      *(uint4*)&Ks[r][seg * 8] = *(const uint4*)&Kt[base + (size_t)(kt * 64 + r) * DD + seg * 8];
      *(uint4*)&Vs[r][seg * 8] = *(const uint4*)&VT[vtb + (size_t)r * LL + kt * 64 + seg * 8];
    }
    __syncthreads();

    // S^T = K·Q^T: rows = keys (quad*4+r), cols = queries (l16)
#pragma unroll
    for (int n = 0; n < 4; ++n) {
      frag_ab ak0 = *(const frag_ab*)&Ks[n * 16 + l16][quad * 8];
      frag_ab ak1 = *(const frag_ab*)&Ks[n * 16 + l16][32 + quad * 8];
      frag_cd z; z[0] = z[1] = z[2] = z[3] = 0.f;
      z = __builtin_amdgcn_mfma_f32_16x16x32_bf16(ak0, bq0, z, 0, 0, 0);
      z = __builtin_amdgcn_mfma_f32_16x16x32_bf16(ak1, bq1, z, 0, 0, 0);
      // P^T regs: key = n*16+quad*4+r, query = w*16+l16
      float p0 = __expf(z[0] * 0.125f - 12.f);
      float p1 = __expf(z[1] * 0.125f - 12.f);
      float p2 = __expf(z[2] * 0.125f - 12.f);
      float p3 = __expf(z[3] * 0.125f - 12.f);
      lsum += p0 + p1 + p2 + p3;
      // truncation-pack to bf16 pairs (bias cancels in O/l)
      unsigned int u01 = __builtin_amdgcn_perm(fbits(p1), fbits(p0), 0x07060302u);
      unsigned int u23 = __builtin_amdgcn_perm(fbits(p3), fbits(p2), 0x07060302u);
      uint2 pk; pk.x = u01; pk.y = u23;
      *(uint2*)&Ps[w * 16 + l16][n * 16 + quad * 4] = pk;   // P[query][key], b64
    }

    // O += P V   (A = P[query][key] from Ps, B = V^T from Vs; wave-local)
    frag_ab ap0 = *(const frag_ab*)&Ps[w * 16 + l16][quad * 8];
    frag_ab ap1 = *(const frag_ab*)&Ps[w * 16 + l16][32 + quad * 8];
#pragma unroll
    for (int n = 0; n < 4; ++n) {
      frag_ab bv0 = *(const frag_ab*)&Vs[n * 16 + l16][quad * 8];
      frag_ab bv1 = *(const frag_ab*)&Vs[n * 16 + l16][32 + quad * 8];
      o_[n] = __builtin_amdgcn_mfma_f32_16x16x32_bf16(ap0, bv0, o_[n], 0, 0, 0);
      o_[n] = __builtin_amdgcn_mfma_f32_16x16x32_bf16(ap1, bv1, o_[n], 0, 0, 0);
    }
  }

  // finish l: reduce over quads (lanes share query l16), then fetch per-row
  lsum += __shfl_xor(lsum, 16);
  lsum += __shfl_xor(lsum, 32);
  float lfin[4];
#pragma unroll
  for (int r = 0; r < 4; ++r) lfin[r] = __shfl(lsum, quad * 4 + r);

#pragma unroll
  for (int n = 0; n < 4; ++n)
#pragma unroll
    for (int r = 0; r < 4; ++r) {
      const float v = o_[n][r] / lfin[r];
      O[base + (size_t)(q0 + w * 16 + quad * 4 + r) * DD + n * 16 + l16] = f2b(v);
    }
}

// layernorm(hidden(bf16) + X) * gamma + beta -> FP32 out
__global__ __launch_bounds__(256) void ln_kernel(const bf16_t* __restrict__ hidden,
                                                 const float* __restrict__ x0,
                                                 const float* __restrict__ gamma,
                                                 const float* __restrict__ beta,
                                                 float* __restrict__ out) {
  const int row = blockIdx.x;
  const int tid = threadIdx.x;
  __shared__ float red1[4], red2[4];
  float v[4];
  float s1 = 0.f, s2 = 0.f;
#pragma unroll
  for (int s = 0; s < 4; ++s) {
    const int c = tid + s * 256;
    const float x = b2f(hidden[(size_t)row * DD + c]) + x0[(size_t)row * DD + c];
    v[s] = x; s1 += x; s2 += x * x;
  }
  s1 = waveSum(s1); s2 = waveSum(s2);
  if ((tid & 63) == 0) { red1[tid >> 6] = s1; red2[tid >> 6] = s2; }
  __syncthreads();
  const float t1 = red1[0] + red1[1] + red1[2] + red1[3];
  const float t2 = red2[0] + red2[1] + red2[2] + red2[3];
  const float mu = t1 * (1.f / DD);
  const float var = t2 * (1.f / DD) - mu * mu;
  const float inv = rsqrtf(var + 1e-12f);
#pragma unroll
  for (int s = 0; s < 4; ++s) {
    const int c = tid + s * 256;
    out[(size_t)row * DD + c] = (v[s] - mu) * inv * gamma[c] + beta[c];
  }
}

// ---------------------------------------------------------------------------
extern "C" void kernel_launch(void* const* d_in, const int* in_sizes, int n_in,
                              void* d_out, int out_size, void* d_ws, size_t ws_size,
                              hipStream_t stream) {
  const float* X    = (const float*)d_in[0];
  const float* Wq   = (const float*)d_in[1];
  const float* bq   = (const float*)d_in[2];
  const float* Wk   = (const float*)d_in[3];
  const float* bk   = (const float*)d_in[4];
  const float* Wv   = (const float*)d_in[5];
  const float* bv   = (const float*)d_in[6];
  const float* Wd   = (const float*)d_in[7];
  const float* bd   = (const float*)d_in[8];
  const float* gam  = (const float*)d_in[9];
  const float* bet  = (const float*)d_in[10];
  const float* delt = (const float*)d_in[11];
  const float* beul = (const float*)d_in[12];
  const float* lsc  = (const float*)d_in[13];
  float* out = (float*)d_out;

  char* w = (char*)d_ws;
  const size_t MB = 1024ull * 1024ull;
  bf16_t* Xb  = (bf16_t*)(w + 0 * MB);    // 8MB
  bf16_t* Wvb = (bf16_t*)(w + 8 * MB);    // 2MB
  bf16_t* Wdb = (bf16_t*)(w + 10 * MB);   // 2MB
  bf16_t* WqT = (bf16_t*)(w + 12 * MB);   // 2MB
  bf16_t* WkT = (bf16_t*)(w + 14 * MB);   // 2MB
  bf16_t* Pq  = (bf16_t*)(w + 16 * MB);   // 4MB
  bf16_t* Pk  = (bf16_t*)(w + 20 * MB);   // 4MB
  bf16_t* Wp  = (bf16_t*)(w + 24 * MB);   // 8MB: W'q[2], W'k[2]
  bf16_t* vb  = (bf16_t*)(w + 32 * MB);   // 8MB  (dead after transpose_v)
  bf16_t* qs  = (bf16_t*)(w + 40 * MB);   // 8MB
  bf16_t* ks  = (bf16_t*)(w + 48 * MB);   // 8MB
  bf16_t* vbT = (bf16_t*)(w + 56 * MB);   // 8MB
  bf16_t* ctx = (bf16_t*)(w + 64 * MB);   // 8MB
  bf16_t* hid = (bf16_t*)(w + 24 * MB);   // 8MB bf16, overlays Wp (dead after attn)
  float*  xmean  = (float*)(w + 72 * MB);             // 8KB
  float*  scores = (float*)(w + 72 * MB + 16384);     // 16KB
  float*  bsum   = (float*)(w + 72 * MB + 32768);     // 16KB
  float*  bias4  = (float*)(w + 72 * MB + 49152);     // 16KB

  const size_t WSZ = (size_t)DD * DD;

  // 0) casts + W transposes
  cast_f2b<<<dim3(4096), 256, 0, stream>>>(X, Xb, BB * LL * DD / 4);
  cast_wvd<<<dim3(1024, 1, 2), 256, 0, stream>>>(Wv, Wd, Wvb, Wdb);
  cast_transpose_w<<<dim3(16, 16, 2), 256, 0, stream>>>(Wq, Wk, WqT, WkT);

  // 1) scores via linearity (exact fp32)
  hipMemsetAsync(xmean, 0, BB * DD * sizeof(float), stream);
  xmean_kernel<<<dim3(4, 32, 2), 256, 0, stream>>>(X, xmean);
  scores_gemm<<<dim3(1024), 256, 0, stream>>>(xmean, Wq, bq, Wk, bk, scores);

  // 2) neural sort P (+ folded bias')
  bsum_kernel<<<dim3(4, 4), 256, 0, stream>>>(scores, bsum);
  p_kernel<<<dim3(1024, 4), 256, 0, stream>>>(scores, bsum, bq, bk, Pq, Pk, bias4);

  // 3) W' = P · W  (gemm64: 512 blocks, 2/CU)
  GemmArgs gw = {};
  gw.gb[0] = {Pq,       WqT, nullptr, nullptr, Wp};
  gw.gb[1] = {Pq + WSZ, WqT, nullptr, nullptr, Wp + WSZ};
  gw.gb[2] = {Pk,       WkT, nullptr, nullptr, Wp + 2 * WSZ};
  gw.gb[3] = {Pk + WSZ, WkT, nullptr, nullptr, Wp + 3 * WSZ};
  gemm64<<<dim3(8, 16, 4), 256, 0, stream>>>(gw, DD, DD, DD);

  // 4) qs/ks/vb (gemm128, 768 blocks, 3/CU)
  const size_t XHALF = (size_t)LL * DD;
  GemmArgs gs = {};
  gs.gb[0] = {Xb,         Wp,           bias4,        nullptr, qs};
  gs.gb[1] = {Xb + XHALF, Wp + WSZ,     bias4 + 1024, nullptr, qs + XHALF};
  gs.gb[2] = {Xb,         Wp + 2 * WSZ, bias4 + 2048, nullptr, ks};
  gs.gb[3] = {Xb + XHALF, Wp + 3 * WSZ, bias4 + 3072, nullptr, ks + XHALF};
  gs.gb[4] = {Xb,         Wvb,          bv,           nullptr, vb};
  gs.gb[5] = {Xb + XHALF, Wvb,          bv,           nullptr, vb + XHALF};
  gemm128<<<dim3(8, 16, 6), 256, 0, stream>>>(gs, LL, DD, DD);

  // 5) V transpose + euler
  transpose_v<<<dim3(32, 16, 2), 256, 0, stream>>>(vb, vbT);
  euler_kernel<<<dim3(8192, 2), 256, 0, stream>>>(qs, ks, delt, beul, lsc);

  // 6) attention (XCD-swizzled, S^T form)
  attn_kernel<<<dim3(1024), 256, 0, stream>>>(qs, ks, vbT, ctx);

  // 7) output projection (gemm64, bf16 hid)
  GemmArgs g4 = {};
  g4.gb[0] = {ctx, Wdb, bd, nullptr, hid};
  gemm64<<<dim3(8, 64, 1), 256, 0, stream>>>(g4, BB * LL, DD, DD);

  // 8) layernorm + residual -> fp32
  ln_kernel<<<dim3(BB * LL), 256, 0, stream>>>(hid, X, gam, bet, out);
}

// Round 16
// 309.269 us; speedup vs baseline: 33.2843x; 1.0358x over previous
//
#include <hip/hip_runtime.h>

// ---------------------------------------------------------------------------
// Euler Attention forward, MI355X gfx950 — ROUND 16.
// r15: 320us; attn VALU-issue-bound (~180 VALU vs 80 MFMA cyc/tile).
// Changes: (1) attn: exp2-folding (scale into q at euler, offset into MFMA
// acc init -> 1 v_exp per P entry) + row-sum l via ones-column MFMA;
// (2) gemm64x64 for gw/g4 -> 1024 blocks = 4/CU (r14 trend continued);
// (3) merged prep casts (+xmean zero) and transpose+euler launches.
// ---------------------------------------------------------------------------

typedef unsigned short bf16_t;
typedef short frag_ab __attribute__((ext_vector_type(8)));   // 8 bf16 = 4 VGPRs
typedef float frag_cd __attribute__((ext_vector_type(4)));   // 4 fp32 acc

#define BB 2
#define LL 2048
#define DD 1024
#define HH 16
#define DH 64

#define QSCALE 0.18033688f     // 0.125 * log2(e)
#define EOFF  -17.3123404907f  // -12 * log2(e)

__device__ __forceinline__ float b2f(bf16_t u) {
  union { unsigned int i; float f; } c; c.i = ((unsigned int)u) << 16; return c.f;
}
__device__ __forceinline__ bf16_t f2b(float f) {
  union { float f; unsigned int i; } c; c.f = f;
  unsigned int r = c.i + 0x7fffu + ((c.i >> 16) & 1u);
  return (bf16_t)(r >> 16);
}
__device__ __forceinline__ unsigned int fbits(float f) {
  union { float f; unsigned int i; } c; c.f = f; return c.i;
}
__device__ __forceinline__ float waveMax(float v) {
#pragma unroll
  for (int m = 32; m > 0; m >>= 1) v = fmaxf(v, __shfl_xor(v, m));
  return v;
}
__device__ __forceinline__ float waveSum(float v) {
#pragma unroll
  for (int m = 32; m > 0; m >>= 1) v += __shfl_xor(v, m);
  return v;
}

// async global->LDS, 16B/lane; lds base wave-uniform (HW adds lane*16)
__device__ __forceinline__ void gll16(const bf16_t* g, bf16_t* l) {
  __builtin_amdgcn_global_load_lds(
      (const __attribute__((address_space(1))) void*)g,
      (__attribute__((address_space(3))) void*)l, 16, 0, 0);
}

// merged prep: X cast (blocks 0..4095), Wv cast (4096..5119),
// Wd cast (5120..6143), xmean zero (6144)
__global__ __launch_bounds__(256) void prep_cast(const float* __restrict__ X,
                                                 const float* __restrict__ Wv,
                                                 const float* __restrict__ Wd,
                                                 bf16_t* __restrict__ Xb,
                                                 bf16_t* __restrict__ Wvb,
                                                 bf16_t* __restrict__ Wdb,
                                                 float* __restrict__ xmean) {
  const int bid = blockIdx.x;
  if (bid == 6144) {
    if (threadIdx.x < 256)
      for (int i = threadIdx.x; i < BB * DD; i += 256) xmean[i] = 0.f;
    return;
  }
  const float* in;
  bf16_t* out;
  int i;
  if (bid < 4096)      { in = X;  out = Xb;  i = bid * 256 + threadIdx.x; }
  else if (bid < 5120) { in = Wv; out = Wvb; i = (bid - 4096) * 256 + threadIdx.x; }
  else                 { in = Wd; out = Wdb; i = (bid - 5120) * 256 + threadIdx.x; }
  float4 v = ((const float4*)in)[i];
  ushort4 o;
  o.x = f2b(v.x); o.y = f2b(v.y); o.z = f2b(v.z); o.w = f2b(v.w);
  ((ushort4*)out)[i] = o;
}

// cast + transpose 1024x1024 fp32 W -> bf16 W^T (z: 0=Wq, 1=Wk)
__global__ __launch_bounds__(256) void cast_transpose_w(const float* __restrict__ Wq,
                                                        const float* __restrict__ Wk,
                                                        bf16_t* __restrict__ WqT,
                                                        bf16_t* __restrict__ WkT) {
  const float* W = blockIdx.z ? Wk : Wq;
  bf16_t* WT = blockIdx.z ? WkT : WqT;
  __shared__ bf16_t T[64][72];
  const int i0 = blockIdx.x * 64, m0 = blockIdx.y * 64;
  const int tid = threadIdx.x;
#pragma unroll
  for (int it = 0; it < 4; ++it) {
    const int idx = tid + it * 256;
    const int r = idx >> 4, c4 = (idx & 15) * 4;
    float4 v = *(const float4*)&W[(size_t)(i0 + r) * DD + m0 + c4];
    T[c4 + 0][r] = f2b(v.x);
    T[c4 + 1][r] = f2b(v.y);
    T[c4 + 2][r] = f2b(v.z);
    T[c4 + 3][r] = f2b(v.w);
  }
  __syncthreads();
#pragma unroll
  for (int it = 0; it < 2; ++it) {
    const int idx = tid + it * 256;
    const int r = idx >> 3, seg = idx & 7;
    *(uint4*)&WT[(size_t)(m0 + r) * DD + i0 + seg * 8] = *(const uint4*)&T[r][seg * 8];
  }
}

// ---------------------------------------------------------------------------
struct GemmB { const bf16_t* A; const bf16_t* Bm; const float* bias; float* Cf; bf16_t* Cb; };
struct GemmArgs { GemmB gb[6]; };

// 128x128 tile MFMA GEMM (4 waves 2x2, each 64x64)
__global__ __launch_bounds__(256) void gemm128(GemmArgs ga, int M, int N, int K) {
  const GemmB g = ga.gb[blockIdx.z];
  const int bm = blockIdx.y * 128, bn = blockIdx.x * 128;
  __shared__ bf16_t As[128][32];
  __shared__ bf16_t Bs[128][32];
  bf16_t* As_f = &As[0][0];
  bf16_t* Bs_f = &Bs[0][0];
  const int tid = threadIdx.x;
  const int lane = tid & 63, w = tid >> 6;
  const int quad = lane >> 4, l16 = lane & 15;
  const int wm = (w >> 1) * 64, wn = (w & 1) * 64;
  const int wbase = w << 9;

  frag_cd acc[4][4];
#pragma unroll
  for (int i = 0; i < 4; ++i)
#pragma unroll
    for (int j = 0; j < 4; ++j)
#pragma unroll
      for (int r = 0; r < 4; ++r) acc[i][j][r] = 0.f;

  const int r0 = tid >> 2, s0 = (tid & 3) * 8;
  const int r1 = (tid + 256) >> 2, s1 = ((tid + 256) & 3) * 8;
  const size_t aoff0 = (size_t)(bm + r0) * K + s0;
  const size_t aoff1 = (size_t)(bm + r1) * K + s1;
  const size_t boff0 = (size_t)(bn + r0) * K + s0;
  const size_t boff1 = (size_t)(bn + r1) * K + s1;

  for (int k0 = 0; k0 < K; k0 += 32) {
    __syncthreads();
    gll16(g.A + aoff0 + k0, As_f + wbase);
    gll16(g.A + aoff1 + k0, As_f + 2048 + wbase);
    gll16(g.Bm + boff0 + k0, Bs_f + wbase);
    gll16(g.Bm + boff1 + k0, Bs_f + 2048 + wbase);
    __syncthreads();
    frag_ab af[4], bfr[4];
#pragma unroll
    for (int i = 0; i < 4; ++i) {
      af[i]  = *(const frag_ab*)&As[wm + i * 16 + l16][quad * 8];
      bfr[i] = *(const frag_ab*)&Bs[wn + i * 16 + l16][quad * 8];
    }
#pragma unroll
    for (int i = 0; i < 4; ++i)
#pragma unroll
      for (int j = 0; j < 4; ++j)
        acc[i][j] = __builtin_amdgcn_mfma_f32_16x16x32_bf16(af[i], bfr[j], acc[i][j], 0, 0, 0);
  }

#pragma unroll
  for (int i = 0; i < 4; ++i) {
#pragma unroll
    for (int r = 0; r < 4; ++r) {
      const int row = bm + wm + i * 16 + quad * 4 + r;
#pragma unroll
      for (int j = 0; j < 4; ++j) {
        const int col = bn + wn + j * 16 + l16;
        float v = acc[i][j][r];
        if (g.bias) v += g.bias[col];
        if (g.Cf) g.Cf[(size_t)row * N + col] = v;
        if (g.Cb) g.Cb[(size_t)row * N + col] = f2b(v);
      }
    }
  }
}

// 64x64 tile MFMA GEMM (4 waves 2x2, each 32x32) — max occupancy variant
__global__ __launch_bounds__(256) void gemm64x64(GemmArgs ga, int M, int N, int K) {
  const GemmB g = ga.gb[blockIdx.z];
  const int bm = blockIdx.y * 64, bn = blockIdx.x * 64;
  __shared__ bf16_t As[64][32];
  __shared__ bf16_t Bs[64][32];
  bf16_t* As_f = &As[0][0];
  bf16_t* Bs_f = &Bs[0][0];
  const int tid = threadIdx.x;
  const int lane = tid & 63, w = tid >> 6;
  const int quad = lane >> 4, l16 = lane & 15;
  const int wm = (w >> 1) * 32, wn = (w & 1) * 32;
  const int wbase = w << 9;

  frag_cd acc[2][2];
#pragma unroll
  for (int i = 0; i < 2; ++i)
#pragma unroll
    for (int j = 0; j < 2; ++j)
#pragma unroll
      for (int r = 0; r < 4; ++r) acc[i][j][r] = 0.f;

  const int r0 = tid >> 2, s0 = (tid & 3) * 8;
  const size_t aoff0 = (size_t)(bm + r0) * K + s0;
  const size_t boff0 = (size_t)(bn + r0) * K + s0;

  for (int k0 = 0; k0 < K; k0 += 32) {
    __syncthreads();
    gll16(g.A + aoff0 + k0, As_f + wbase);
    gll16(g.Bm + boff0 + k0, Bs_f + wbase);
    __syncthreads();
    frag_ab af[2], bfr[2];
#pragma unroll
    for (int i = 0; i < 2; ++i) {
      af[i]  = *(const frag_ab*)&As[wm + i * 16 + l16][quad * 8];
      bfr[i] = *(const frag_ab*)&Bs[wn + i * 16 + l16][quad * 8];
    }
#pragma unroll
    for (int i = 0; i < 2; ++i)
#pragma unroll
      for (int j = 0; j < 2; ++j)
        acc[i][j] = __builtin_amdgcn_mfma_f32_16x16x32_bf16(af[i], bfr[j], acc[i][j], 0, 0, 0);
  }

#pragma unroll
  for (int i = 0; i < 2; ++i) {
#pragma unroll
    for (int r = 0; r < 4; ++r) {
      const int row = bm + wm + i * 16 + quad * 4 + r;
#pragma unroll
      for (int j = 0; j < 2; ++j) {
        const int col = bn + wn + j * 16 + l16;
        float v = acc[i][j][r];
        if (g.bias) v += g.bias[col];
        if (g.Cf) g.Cf[(size_t)row * N + col] = v;
        if (g.Cb) g.Cb[(size_t)row * N + col] = f2b(v);
      }
    }
  }
}

// xmean[b][d] = mean over L of X[b][l][d]
__global__ __launch_bounds__(256) void xmean_kernel(const float* __restrict__ X,
                                                    float* __restrict__ xmean) {
  const int d = blockIdx.x * 256 + threadIdx.x;
  const int b = blockIdx.z;
  const int l0 = blockIdx.y * 64;
  float s = 0.f;
  for (int l = l0; l < l0 + 64; ++l)
    s += X[((size_t)b * LL + l) * DD + d];
  atomicAdd(&xmean[b * DD + d], s * (1.f / (float)LL));
}

// scores: one wave per output
__global__ __launch_bounds__(256) void scores_gemm(const float* __restrict__ xmean,
                                                   const float* __restrict__ Wq,
                                                   const float* __restrict__ bq,
                                                   const float* __restrict__ Wk,
                                                   const float* __restrict__ bk,
                                                   float* __restrict__ scores) {
  const int w = threadIdx.x >> 6, lane = threadIdx.x & 63;
  const int idx = blockIdx.x * 4 + w;
  const int t = idx >> 11, b = (idx >> 10) & 1, i = idx & 1023;
  const float* W = t ? Wk : Wq;
  const float* bias = t ? bk : bq;
  const float* xm = xmean + b * DD;
  float sum = 0.f;
#pragma unroll
  for (int k = 0; k < 4; ++k) {
    float4 wv = *(const float4*)&W[(size_t)i * DD + k * 256 + lane * 4];
    float4 xv = *(const float4*)&xm[k * 256 + lane * 4];
    sum += wv.x * xv.x + wv.y * xv.y + wv.z * xv.z + wv.w * xv.w;
  }
  sum = waveSum(sum);
  if (lane == 0) scores[idx] = sum + bias[i];
}

// Bsum: 16 blocks, float4 LDS reads
__global__ __launch_bounds__(256) void bsum_kernel(const float* __restrict__ scores,
                                                   float* __restrict__ bsum) {
  __shared__ float sc[DD];
  const int z = blockIdx.x, jb = blockIdx.y, tid = threadIdx.x;
#pragma unroll
  for (int s = 0; s < 4; ++s) sc[tid + s * 256] = scores[z * DD + tid + s * 256];
  __syncthreads();
  const int j = jb * 256 + tid;
  const float si = sc[j];
  float s = 0.f;
  for (int m = 0; m < DD; m += 4) {
    float4 v = *(const float4*)&sc[m];
    s += fabsf(si - v.x) + fabsf(si - v.y) + fabsf(si - v.z) + fabsf(si - v.w);
  }
  bsum[z * DD + j] = s;
}

// P row + folded bias'
__global__ __launch_bounds__(256) void p_kernel(const float* __restrict__ scores,
                                                const float* __restrict__ bsum,
                                                const float* __restrict__ bq,
                                                const float* __restrict__ bk,
                                                bf16_t* __restrict__ Pq,
                                                bf16_t* __restrict__ Pk,
                                                float* __restrict__ bias4) {
  const int i = blockIdx.x;
  const int z = blockIdx.y;
  const int t = z >> 1, b = z & 1;
  const float* sc = scores + z * DD;
  const float* bs = bsum + z * DD;
  const float* bias = t ? bk : bq;
  const float scal = 1023.f - 2.f * (float)i;
  const int tid = threadIdx.x;
  __shared__ float redA[4], redB[4], redC[4];

  float lg[4], bb[4];
  float mx = -1e30f;
#pragma unroll
  for (int s = 0; s < 4; ++s) {
    const int j = tid + s * 256;
    lg[s] = sc[j] * scal - bs[j];
    bb[s] = bias[j];
    mx = fmaxf(mx, lg[s]);
  }
  mx = waveMax(mx);
  if ((tid & 63) == 0) redA[tid >> 6] = mx;
  __syncthreads();
  const float M = fmaxf(fmaxf(redA[0], redA[1]), fmaxf(redA[2], redA[3]));
  float sum = 0.f, dot = 0.f;
#pragma unroll
  for (int s = 0; s < 4; ++s) {
    lg[s] = __expf(lg[s] - M);
    sum += lg[s];
    dot += lg[s] * bb[s];
  }
  sum = waveSum(sum); dot = waveSum(dot);
  if ((tid & 63) == 0) { redB[tid >> 6] = sum; redC[tid >> 6] = dot; }
  __syncthreads();
  const float inv = 1.f / (redB[0] + redB[1] + redB[2] + redB[3]);
  bf16_t* P = (t ? Pk : Pq) + ((size_t)b << 20) + (size_t)i * DD;
#pragma unroll
  for (int s = 0; s < 4; ++s) P[tid + s * 256] = f2b(lg[s] * inv);
  if (tid == 0)
    bias4[t * 2048 + b * 1024 + i] = (redC[0] + redC[1] + redC[2] + redC[3]) * inv;
}

// merged euler (blocks 0..16383, q scaled by QSCALE) + V transpose (16384..)
__global__ __launch_bounds__(256) void euler_transv(bf16_t* __restrict__ qs,
                                                    bf16_t* __restrict__ ks,
                                                    const float* __restrict__ delta,
                                                    const float* __restrict__ beul,
                                                    const float* __restrict__ lsc,
                                                    const bf16_t* __restrict__ vb,
                                                    bf16_t* __restrict__ vbT) {
  __shared__ bf16_t T[64][72];
  const int bid = blockIdx.x;
  const int tid = threadIdx.x;
  if (bid < 16384) {
    const int isq = (bid < 8192);
    unsigned int* buf = (unsigned int*)(isq ? qs : ks);
    const int idx = (isq ? bid : bid - 8192) * 256 + tid;
    const int c = idx & 511;
    const size_t n = idx >> 9;
    const unsigned int u = buf[n * 512 + c];
    const float r = b2f((bf16_t)(u & 0xffffu));
    const float p = b2f((bf16_t)(u >> 16));
    float lam = sqrtf(r * r + p * p + 1e-6f);
    float th = atan2f(p, r) * delta[c];
    if (isq) th += beul[c];
    lam *= __expf(fminf(fmaxf(lsc[c], -5.f), 5.f));
    if (isq) lam *= QSCALE;    // fold attention scale into q (q only feeds attn)
    float sn, cs;
    __sincosf(th, &sn, &cs);
    buf[n * 512 + c] = ((unsigned int)f2b(lam * sn) << 16) | (unsigned int)f2b(lam * cs);
    return;
  }
  const int tb = bid - 16384;                 // 0..1023: (32, 16, 2)
  const int l0 = (tb & 31) * 64, d0 = ((tb >> 5) & 15) * 64, b = tb >> 9;
  for (int i = tid; i < 512; i += 256) {
    const int r = i >> 3, seg = i & 7;
    uint4 v = *(const uint4*)&vb[((size_t)b * LL + l0 + r) * DD + d0 + seg * 8];
    const bf16_t* vs = (const bf16_t*)&v;
#pragma unroll
    for (int j = 0; j < 8; ++j) T[seg * 8 + j][r] = vs[j];
  }
  __syncthreads();
  for (int i = tid; i < 512; i += 256) {
    const int r = i >> 3, seg = i & 7;
    *(uint4*)&vbT[((size_t)b * DD + d0 + r) * LL + l0 + seg * 8] =
        *(const uint4*)&T[r][seg * 8];
  }
}

// ---------------------------------------------------------------------------
// Flash attention v4: S^T form, exp2-folded (q pre-scaled, offset in acc
// init -> 1 v_exp per P entry), row-sum l via ones-column MFMA.
// ---------------------------------------------------------------------------
__global__ __launch_bounds__(256) void attn_kernel(const bf16_t* __restrict__ Q,
                                                   const bf16_t* __restrict__ Kt,
                                                   const bf16_t* __restrict__ VT,
                                                   bf16_t* __restrict__ O) {
  const int bid = blockIdx.x;
  const int g = (bid & 7) + 8 * (bid >> 8);
  const int qt = (bid >> 3) & 31;
  const int b = g >> 4, h = g & 15;
  const int q0 = qt * 64;
  const int tid = threadIdx.x, w = tid >> 6, lane = tid & 63;
  const int quad = lane >> 4, l16 = lane & 15;
  __shared__ bf16_t Ks[64][72], Vs[80][72], Ps[64][72], Qs[64][72];
  const size_t base = ((size_t)b * LL) * DD + (size_t)h * DH;
  const size_t vtb = (size_t)(b * DD + h * DH) * LL;

  // ones-column rows: Vs[64] = 1.0, Vs[65..79] = 0
  for (int i = tid; i < 16 * 72; i += 256) {
    const int r = i / 72;
    Vs[64 + r][i % 72] = (r == 0) ? (bf16_t)0x3F80 : (bf16_t)0;
  }
  for (int i = tid; i < 512; i += 256) {
    const int r = i >> 3, seg = i & 7;
    *(uint4*)&Qs[r][seg * 8] = *(const uint4*)&Q[base + (size_t)(q0 + r) * DD + seg * 8];
  }
  __syncthreads();
  frag_ab bq0 = *(const frag_ab*)&Qs[w * 16 + l16][quad * 8];
  frag_ab bq1 = *(const frag_ab*)&Qs[w * 16 + l16][32 + quad * 8];

  frag_cd o_[4], l5;
#pragma unroll
  for (int n = 0; n < 4; ++n)
#pragma unroll
    for (int r = 0; r < 4; ++r) o_[n][r] = 0.f;
#pragma unroll
  for (int r = 0; r < 4; ++r) l5[r] = 0.f;

  for (int kt = 0; kt < LL / 64; ++kt) {
    __syncthreads();
    for (int i = tid; i < 512; i += 256) {
      const int r = i >> 3, seg = i & 7;
      *(uint4*)&Ks[r][seg * 8] = *(const uint4*)&Kt[base + (size_t)(kt * 64 + r) * DD + seg * 8];
      *(uint4*)&Vs[r][seg * 8] = *(const uint4*)&VT[vtb + (size_t)r * LL + kt * 64 + seg * 8];
    }
    __syncthreads();

    // S^T = K·Q'^T + EOFF (acc-init): p = exp2(z), single v_exp each
#pragma unroll
    for (int n = 0; n < 4; ++n) {
      frag_ab ak0 = *(const frag_ab*)&Ks[n * 16 + l16][quad * 8];
      frag_ab ak1 = *(const frag_ab*)&Ks[n * 16 + l16][32 + quad * 8];
      frag_cd z; z[0] = z[1] = z[2] = z[3] = EOFF;
      z = __builtin_amdgcn_mfma_f32_16x16x32_bf16(ak0, bq0, z, 0, 0, 0);
      z = __builtin_amdgcn_mfma_f32_16x16x32_bf16(ak1, bq1, z, 0, 0, 0);
      float p0 = __builtin_amdgcn_exp2f(z[0]);
      float p1 = __builtin_amdgcn_exp2f(z[1]);
      float p2 = __builtin_amdgcn_exp2f(z[2]);
      float p3 = __builtin_amdgcn_exp2f(z[3]);
      unsigned int u01 = __builtin_amdgcn_perm(fbits(p1), fbits(p0), 0x07060302u);
      unsigned int u23 = __builtin_amdgcn_perm(fbits(p3), fbits(p2), 0x07060302u);
      uint2 pk; pk.x = u01; pk.y = u23;
      *(uint2*)&Ps[w * 16 + l16][n * 16 + quad * 4] = pk;   // P[query][key]
    }

    // O += P V ; l += P · 1  (ones-column MFMA, same A-frags)
    frag_ab ap0 = *(const frag_ab*)&Ps[w * 16 + l16][quad * 8];
    frag_ab ap1 = *(const frag_ab*)&Ps[w * 16 + l16][32 + quad * 8];
#pragma unroll
    for (int n = 0; n < 4; ++n) {
      frag_ab bv0 = *(const frag_ab*)&Vs[n * 16 + l16][quad * 8];
      frag_ab bv1 = *(const frag_ab*)&Vs[n * 16 + l16][32 + quad * 8];
      o_[n] = __builtin_amdgcn_mfma_f32_16x16x32_bf16(ap0, bv0, o_[n], 0, 0, 0);
      o_[n] = __builtin_amdgcn_mfma_f32_16x16x32_bf16(ap1, bv1, o_[n], 0, 0, 0);
    }
    frag_ab bo0 = *(const frag_ab*)&Vs[64 + l16][quad * 8];
    frag_ab bo1 = *(const frag_ab*)&Vs[64 + l16][32 + quad * 8];
    l5 = __builtin_amdgcn_mfma_f32_16x16x32_bf16(ap0, bo0, l5, 0, 0, 0);
    l5 = __builtin_amdgcn_mfma_f32_16x16x32_bf16(ap1, bo1, l5, 0, 0, 0);
  }

  // l for query quad*4+r lives at lane quad*16 (col 0), reg r
  float lfin[4];
#pragma unroll
  for (int r = 0; r < 4; ++r) lfin[r] = 1.f / __shfl(l5[r], quad << 4);

#pragma unroll
  for (int n = 0; n < 4; ++n)
#pragma unroll
    for (int r = 0; r < 4; ++r) {
      const float v = o_[n][r] * lfin[r];
      O[base + (size_t)(q0 + w * 16 + quad * 4 + r) * DD + n * 16 + l16] = f2b(v);
    }
}

// layernorm(hidden(bf16) + X) * gamma + beta -> FP32 out
__global__ __launch_bounds__(256) void ln_kernel(const bf16_t* __restrict__ hidden,
                                                 const float* __restrict__ x0,
                                                 const float* __restrict__ gamma,
                                                 const float* __restrict__ beta,
                                                 float* __restrict__ out) {
  const int row = blockIdx.x;
  const int tid = threadIdx.x;
  __shared__ float red1[4], red2[4];
  float v[4];
  float s1 = 0.f, s2 = 0.f;
#pragma unroll
  for (int s = 0; s < 4; ++s) {
    const int c = tid + s * 256;
    const float x = b2f(hidden[(size_t)row * DD + c]) + x0[(size_t)row * DD + c];
    v[s] = x; s1 += x; s2 += x * x;
  }
  s1 = waveSum(s1); s2 = waveSum(s2);
  if ((tid & 63) == 0) { red1[tid >> 6] = s1; red2[tid >> 6] = s2; }
  __syncthreads();
  const float t1 = red1[0] + red1[1] + red1[2] + red1[3];
  const float t2 = red2[0] + red2[1] + red2[2] + red2[3];
  const float mu = t1 * (1.f / DD);
  const float var = t2 * (1.f / DD) - mu * mu;
  const float inv = rsqrtf(var + 1e-12f);
#pragma unroll
  for (int s = 0; s < 4; ++s) {
    const int c = tid + s * 256;
    out[(size_t)row * DD + c] = (v[s] - mu) * inv * gamma[c] + beta[c];
  }
}

// ---------------------------------------------------------------------------
extern "C" void kernel_launch(void* const* d_in, const int* in_sizes, int n_in,
                              void* d_out, int out_size, void* d_ws, size_t ws_size,
                              hipStream_t stream) {
  const float* X    = (const float*)d_in[0];
  const float* Wq   = (const float*)d_in[1];
  const float* bq   = (const float*)d_in[2];
  const float* Wk   = (const float*)d_in[3];
  const float* bk   = (const float*)d_in[4];
  const float* Wv   = (const float*)d_in[5];
  const float* bv   = (const float*)d_in[6];
  const float* Wd   = (const float*)d_in[7];
  const float* bd   = (const float*)d_in[8];
  const float* gam  = (const float*)d_in[9];
  const float* bet  = (const float*)d_in[10];
  const float* delt = (const float*)d_in[11];
  const float* beul = (const float*)d_in[12];
  const float* lsc  = (const float*)d_in[13];
  float* out = (float*)d_out;

  char* w = (char*)d_ws;
  const size_t MB = 1024ull * 1024ull;
  bf16_t* Xb  = (bf16_t*)(w + 0 * MB);    // 8MB
  bf16_t* Wvb = (bf16_t*)(w + 8 * MB);    // 2MB
  bf16_t* Wdb = (bf16_t*)(w + 10 * MB);   // 2MB
  bf16_t* WqT = (bf16_t*)(w + 12 * MB);   // 2MB
  bf16_t* WkT = (bf16_t*)(w + 14 * MB);   // 2MB
  bf16_t* Pq  = (bf16_t*)(w + 16 * MB);   // 4MB
  bf16_t* Pk  = (bf16_t*)(w + 20 * MB);   // 4MB
  bf16_t* Wp  = (bf16_t*)(w + 24 * MB);   // 8MB: W'q[2], W'k[2]
  bf16_t* vb  = (bf16_t*)(w + 32 * MB);   // 8MB  (dead after transpose)
  bf16_t* qs  = (bf16_t*)(w + 40 * MB);   // 8MB
  bf16_t* ks  = (bf16_t*)(w + 48 * MB);   // 8MB
  bf16_t* vbT = (bf16_t*)(w + 56 * MB);   // 8MB
  bf16_t* ctx = (bf16_t*)(w + 64 * MB);   // 8MB
  bf16_t* hid = (bf16_t*)(w + 24 * MB);   // 8MB bf16, overlays Wp (dead after attn)
  float*  xmean  = (float*)(w + 72 * MB);             // 8KB
  float*  scores = (float*)(w + 72 * MB + 16384);     // 16KB
  float*  bsum   = (float*)(w + 72 * MB + 32768);     // 16KB
  float*  bias4  = (float*)(w + 72 * MB + 49152);     // 16KB

  const size_t WSZ = (size_t)DD * DD;

  // 0) merged casts + xmean zero; W transposes
  prep_cast<<<dim3(6145), 256, 0, stream>>>(X, Wv, Wd, Xb, Wvb, Wdb, xmean);
  cast_transpose_w<<<dim3(16, 16, 2), 256, 0, stream>>>(Wq, Wk, WqT, WkT);

  // 1) scores via linearity (exact fp32)
  xmean_kernel<<<dim3(4, 32, 2), 256, 0, stream>>>(X, xmean);
  scores_gemm<<<dim3(1024), 256, 0, stream>>>(xmean, Wq, bq, Wk, bk, scores);

  // 2) neural sort P (+ folded bias')
  bsum_kernel<<<dim3(4, 4), 256, 0, stream>>>(scores, bsum);
  p_kernel<<<dim3(1024, 4), 256, 0, stream>>>(scores, bsum, bq, bk, Pq, Pk, bias4);

  // 3) W' = P · W  (gemm64x64: 1024 blocks, 4/CU)
  GemmArgs gw = {};
  gw.gb[0] = {Pq,       WqT, nullptr, nullptr, Wp};
  gw.gb[1] = {Pq + WSZ, WqT, nullptr, nullptr, Wp + WSZ};
  gw.gb[2] = {Pk,       WkT, nullptr, nullptr, Wp + 2 * WSZ};
  gw.gb[3] = {Pk + WSZ, WkT, nullptr, nullptr, Wp + 3 * WSZ};
  gemm64x64<<<dim3(16, 16, 4), 256, 0, stream>>>(gw, DD, DD, DD);

  // 4) qs/ks/vb (gemm128, 768 blocks, 3/CU)
  const size_t XHALF = (size_t)LL * DD;
  GemmArgs gs = {};
  gs.gb[0] = {Xb,         Wp,           bias4,        nullptr, qs};
  gs.gb[1] = {Xb + XHALF, Wp + WSZ,     bias4 + 1024, nullptr, qs + XHALF};
  gs.gb[2] = {Xb,         Wp + 2 * WSZ, bias4 + 2048, nullptr, ks};
  gs.gb[3] = {Xb + XHALF, Wp + 3 * WSZ, bias4 + 3072, nullptr, ks + XHALF};
  gs.gb[4] = {Xb,         Wvb,          bv,           nullptr, vb};
  gs.gb[5] = {Xb + XHALF, Wvb,          bv,           nullptr, vb + XHALF};
  gemm128<<<dim3(8, 16, 6), 256, 0, stream>>>(gs, LL, DD, DD);

  // 5) euler (q pre-scaled) + V transpose, merged
  euler_transv<<<dim3(17408), 256, 0, stream>>>(qs, ks, delt, beul, lsc, vb, vbT);

  // 6) attention (XCD-swizzled, exp2-folded, MFMA row-sum)
  attn_kernel<<<dim3(1024), 256, 0, stream>>>(qs, ks, vbT, ctx);

  // 7) output projection (gemm64x64: 1024 blocks)
  GemmArgs g4 = {};
  g4.gb[0] = {ctx, Wdb, bd, nullptr, hid};
  gemm64x64<<<dim3(16, 64, 1), 256, 0, stream>>>(g4, BB * LL, DD, DD);

  // 8) layernorm + residual -> fp32
  ln_kernel<<<dim3(BB * LL), 256, 0, stream>>>(hid, X, gam, bet, out);
}